// Round 1
// baseline (509.883 us; speedup 1.0000x reference)
//
#include <hip/hip_runtime.h>
#include <math.h>

#define W_SEQ   2048
#define C_IN    512
#define N_BATCH 4
#define NHEAD   8
#define DHEAD   64
#define QKV_CH  1536
#define OUT_CH  512
#define ATTND   512

// ---------------------------------------------------------------------------
// GEMM1: temp[m, ch] = sum_k input[n, k, i] * W_in[ch, k] + b_in[ch]
//   m = n*W_SEQ + i,  M = N_BATCH*W_SEQ = 8192, N = 1536, K = 512
//   input is (n, c, 1, w): X[m,k] = input[n*C_IN*W_SEQ + k*W_SEQ + i]
// tx -> ch (contiguous store dim of temp), ty -> m
// ---------------------------------------------------------------------------
__global__ __launch_bounds__(256) void gemm_in_k(const float* __restrict__ input,
                                                 const float* __restrict__ Wi,
                                                 const float* __restrict__ bi,
                                                 float* __restrict__ temp)
{
    __shared__ float Xs[16][64 + 1];   // [kk][mm]
    __shared__ float Ws[16][64 + 1];   // [kk][nn]  (nn = output channel)
    const int m0 = blockIdx.y * 64;
    const int c0 = blockIdx.x * 64;
    const int t  = threadIdx.x;
    const int tx = t & 15, ty = t >> 4;
    const int n_i = m0 / W_SEQ;
    const int i0  = m0 % W_SEQ;
    const float* Xbase = input + (size_t)n_i * C_IN * W_SEQ + i0;

    float acc[4][4] = {};
    for (int k0 = 0; k0 < C_IN; k0 += 16) {
        {   // load X tile: 64 m  x 16 k  (coalesced along i)
            int mm = t & 63, kk = t >> 6;           // kk in [0,4)
            #pragma unroll
            for (int s = 0; s < 4; ++s)
                Xs[kk + 4 * s][mm] = Xbase[(size_t)(k0 + kk + 4 * s) * W_SEQ + mm];
        }
        {   // load W tile: 64 ch x 16 k  (coalesced along k)
            int kk = t & 15, nn = t >> 4;           // nn in [0,16)
            #pragma unroll
            for (int s = 0; s < 4; ++s)
                Ws[kk][nn + 16 * s] = Wi[(size_t)(c0 + nn + 16 * s) * C_IN + k0 + kk];
        }
        __syncthreads();
        #pragma unroll
        for (int kk = 0; kk < 16; ++kk) {
            float a[4], b[4];
            #pragma unroll
            for (int i = 0; i < 4; ++i) a[i] = Ws[kk][tx + 16 * i];
            #pragma unroll
            for (int j = 0; j < 4; ++j) b[j] = Xs[kk][ty + 16 * j];
            #pragma unroll
            for (int j = 0; j < 4; ++j)
                #pragma unroll
                for (int i = 0; i < 4; ++i)
                    acc[j][i] = fmaf(a[i], b[j], acc[j][i]);
        }
        __syncthreads();
    }
    #pragma unroll
    for (int j = 0; j < 4; ++j) {
        const int m = m0 + ty + 16 * j;
        #pragma unroll
        for (int i = 0; i < 4; ++i) {
            const int ch = c0 + tx + 16 * i;
            temp[(size_t)m * QKV_CH + ch] = acc[j][i] + bi[ch];
        }
    }
}

// ---------------------------------------------------------------------------
// Attention: one wave per (n, h, i) row, lane = d (DHEAD == 64 == wavefront)
// Online softmax over banded window |i-j| <= 15 with mask[n,j] > 0.5.
//   q = temp[(n*W+i)*1536 + h*192 + d]
//   k = ... + 64 + d,  v = ... + 128 + d
//   attn_out[(n*W+i)*512 + h*64 + d]
// ---------------------------------------------------------------------------
__global__ __launch_bounds__(256) void attn_k(const float* __restrict__ temp,
                                              const float* __restrict__ mask,
                                              float* __restrict__ attn_out)
{
    const int wave = threadIdx.x >> 6;
    const int lane = threadIdx.x & 63;
    const int row  = blockIdx.x * 4 + wave;        // ((n*NHEAD)+h)*W_SEQ + i
    const int i  = row & (W_SEQ - 1);
    const int nh = row >> 11;
    const int h  = nh & (NHEAD - 1);
    const int n  = nh >> 3;

    const float* tb = temp + (size_t)n * W_SEQ * QKV_CH + h * 192;
    const float q = tb[(size_t)i * QKV_CH + lane];

    float m = -1e30f, l = 0.f, acc = 0.f;
    const int j0 = (i - 15 > 0) ? i - 15 : 0;
    const int j1 = (i + 15 < W_SEQ - 1) ? i + 15 : W_SEQ - 1;
    for (int j = j0; j <= j1; ++j) {
        if (mask[n * W_SEQ + j] <= 0.5f) continue;   // wave-uniform branch
        const float* kj = tb + (size_t)j * QKV_CH + 64;
        float s = q * kj[lane];
        #pragma unroll
        for (int off = 32; off; off >>= 1) s += __shfl_xor(s, off, 64);
        s *= 0.015625f;                               // scale = 8/512
        const float mn   = fmaxf(m, s);
        const float corr = expf(m - mn);
        const float p    = expf(s - mn);
        l   = l * corr + p;
        acc = acc * corr + p * kj[lane + 64];         // v
        m = mn;
    }
    const float o = (l > 0.f) ? acc / l : 0.f;
    attn_out[(size_t)(n * W_SEQ + i) * ATTND + h * DHEAD + lane] = o;
}

// ---------------------------------------------------------------------------
// GEMM2: out[n, o, 0, i] = sum_c attn_out[m, c] * W_fc[o, c] + b_fc[o]
//   M = 8192, N = 512, K = 512.  tx -> m (contiguous store dim), ty -> o
// ---------------------------------------------------------------------------
__global__ __launch_bounds__(256) void gemm_out_k(const float* __restrict__ attn_out,
                                                  const float* __restrict__ Wf,
                                                  const float* __restrict__ bf,
                                                  float* __restrict__ out)
{
    __shared__ float As[16][64 + 1];   // [kk][mm]
    __shared__ float Bs[16][64 + 1];   // [kk][oo]
    const int m0 = blockIdx.y * 64;
    const int o0 = blockIdx.x * 64;
    const int t  = threadIdx.x;
    const int tx = t & 15, ty = t >> 4;

    float acc[4][4] = {};
    for (int k0 = 0; k0 < ATTND; k0 += 16) {
        {
            int kk = t & 15, mm = t >> 4;
            #pragma unroll
            for (int s = 0; s < 4; ++s)
                As[kk][mm + 16 * s] = attn_out[(size_t)(m0 + mm + 16 * s) * ATTND + k0 + kk];
        }
        {
            int kk = t & 15, oo = t >> 4;
            #pragma unroll
            for (int s = 0; s < 4; ++s)
                Bs[kk][oo + 16 * s] = Wf[(size_t)(o0 + oo + 16 * s) * ATTND + k0 + kk];
        }
        __syncthreads();
        #pragma unroll
        for (int kk = 0; kk < 16; ++kk) {
            float a[4], b[4];
            #pragma unroll
            for (int i = 0; i < 4; ++i) a[i] = As[kk][tx + 16 * i];   // m
            #pragma unroll
            for (int j = 0; j < 4; ++j) b[j] = Bs[kk][ty + 16 * j];   // o
            #pragma unroll
            for (int j = 0; j < 4; ++j)
                #pragma unroll
                for (int i = 0; i < 4; ++i)
                    acc[j][i] = fmaf(a[i], b[j], acc[j][i]);
        }
        __syncthreads();
    }
    #pragma unroll
    for (int j = 0; j < 4; ++j) {
        const int o = o0 + ty + 16 * j;
        const float bias = bf[o];
        #pragma unroll
        for (int i = 0; i < 4; ++i) {
            const int m  = m0 + tx + 16 * i;
            const int n  = m >> 11;            // / W_SEQ
            const int ii = m & (W_SEQ - 1);
            out[((size_t)n * OUT_CH + o) * W_SEQ + ii] = acc[j][i] + bias;
        }
    }
}

extern "C" void kernel_launch(void* const* d_in, const int* in_sizes, int n_in,
                              void* d_out, int out_size, void* d_ws, size_t ws_size,
                              hipStream_t stream)
{
    const float* input = (const float*)d_in[0];
    const float* mask  = (const float*)d_in[1];
    const float* W_in  = (const float*)d_in[2];
    const float* b_in  = (const float*)d_in[3];
    const float* W_fc  = (const float*)d_in[4];
    const float* b_fc  = (const float*)d_in[5];
    float* out = (float*)d_out;

    float* temp     = (float*)d_ws;                           // 8192*1536 f32 = 50.3 MB
    float* attn_out = temp + (size_t)8192 * QKV_CH;           // 8192*512  f32 = 16.8 MB

    const dim3 blk(256);
    gemm_in_k <<<dim3(QKV_CH / 64, (N_BATCH * W_SEQ) / 64), blk, 0, stream>>>(input, W_in, b_in, temp);
    attn_k    <<<dim3((N_BATCH * NHEAD * W_SEQ) / 4),       blk, 0, stream>>>(temp, mask, attn_out);
    gemm_out_k<<<dim3(OUT_CH / 64, (N_BATCH * W_SEQ) / 64), blk, 0, stream>>>(attn_out, W_fc, b_fc, out);
}

// Round 2
// 231.824 us; speedup vs baseline: 2.1994x; 2.1994x over previous
//
#include <hip/hip_runtime.h>
#include <hip/hip_bf16.h>
#include <math.h>

#define W_SEQ   2048
#define C_IN    512
#define N_BATCH 4
#define NHEAD   8
#define QKV_CH  1536
#define OUT_CH  512
#define ATTND   512

typedef __attribute__((ext_vector_type(8))) short bf16x8;
typedef __attribute__((ext_vector_type(4))) float f32x4;

__device__ __forceinline__ void gld16(const void* g, void* l) {
    __builtin_amdgcn_global_load_lds((const __attribute__((address_space(1))) void*)g,
                                     (__attribute__((address_space(3))) void*)l, 16, 0, 0);
}

// ---------------------------------------------------------------------------
// prep_x: input (n, c, 1, w) f32 -> Xhi/Xlo [m = n*W + i][k = c] bf16 planes
// (transpose c<->i per batch via LDS tile)
// ---------------------------------------------------------------------------
__global__ __launch_bounds__(256) void prep_x_k(const float* __restrict__ in,
                                                __hip_bfloat16* __restrict__ xh,
                                                __hip_bfloat16* __restrict__ xl)
{
    __shared__ float ts[64][65];
    const int n = blockIdx.z, i0 = blockIdx.x * 64, c0 = blockIdx.y * 64;
    const int tx = threadIdx.x & 63, ty = threadIdx.x >> 6;
    #pragma unroll
    for (int s = 0; s < 16; ++s) {
        const int c = s * 4 + ty;
        ts[c][tx] = in[((size_t)(n * C_IN + c0 + c)) * W_SEQ + i0 + tx];
    }
    __syncthreads();
    #pragma unroll
    for (int s = 0; s < 16; ++s) {
        const int i = s * 4 + ty;
        const float v = ts[tx][i];
        const __hip_bfloat16 h = __float2bfloat16(v);
        const float lo = v - __bfloat162float(h);
        const size_t idx = ((size_t)(n * W_SEQ + i0 + i)) * C_IN + c0 + tx;
        xh[idx] = h;
        xl[idx] = __float2bfloat16(lo);
    }
}

// ---------------------------------------------------------------------------
// prep_w: f32 matrix -> hi/lo bf16 planes (same layout)
// ---------------------------------------------------------------------------
__global__ __launch_bounds__(256) void prep_w_k(const float* __restrict__ w,
                                                __hip_bfloat16* __restrict__ wh,
                                                __hip_bfloat16* __restrict__ wl, int nelem)
{
    const int idx = blockIdx.x * 256 + threadIdx.x;
    if (idx >= nelem) return;
    const float v = w[idx];
    const __hip_bfloat16 h = __float2bfloat16(v);
    wh[idx] = h;
    wl[idx] = __float2bfloat16(v - __bfloat162float(h));
}

// ---------------------------------------------------------------------------
// Split-bf16 MFMA GEMM: C = A * B^T (+bias), K = 512 fixed.
//   A planes: [M][512] bf16 (hi/lo), B planes: [N][512] bf16 (hi/lo)
//   acc += Ahi*Bhi + Alo*Bhi + Ahi*Blo  (fp32-equivalent)
// Tile 128x128x64, 4 waves, 16x16x32 MFMA, global_load_lds w/ XOR swizzle.
// EPI 0: C[row*ldc + col] = acc + bias[col]            (GEMM1: temp)
// EPI 1: C[((col>>11)*512 + row)*2048 + (col&2047)] = acc + bias[row]  (GEMM2)
// ---------------------------------------------------------------------------
template<int EPI>
__global__ __launch_bounds__(256, 2) void gemm_split(
    const __hip_bfloat16* __restrict__ Ah, const __hip_bfloat16* __restrict__ Al,
    const __hip_bfloat16* __restrict__ Bh, const __hip_bfloat16* __restrict__ Bl,
    const float* __restrict__ bias, float* __restrict__ C, const int ldc)
{
    __shared__ __align__(16) char sm[65536];
    const int t = threadIdx.x;
    const int l = t & 63, w = t >> 6;
    const int m0 = blockIdx.y * 128, n0 = blockIdx.x * 128;
    const int wm = w >> 1, wn = w & 1;

    // staging lane constants: LDS linear slot (q*1024 + l*16) <-> row q*8+(l>>3),
    // col (l&7)*16; swizzled source col = ((l&7) ^ (l>>3)) << 4
    const int subrow = l >> 3;
    const int swz    = ((l & 7) ^ subrow) << 4;
    const char* pAh = (const char*)Ah + (size_t)m0 * 1024 + swz;
    const char* pAl = (const char*)Al + (size_t)m0 * 1024 + swz;
    const char* pBh = (const char*)Bh + (size_t)n0 * 1024 + swz;
    const char* pBl = (const char*)Bl + (size_t)n0 * 1024 + swz;

    const int frow = l & 15;
    f32x4 acc[4][4] = {};

    for (int k0 = 0; k0 < 512; k0 += 64) {
        const int kb = k0 * 2;
        #pragma unroll
        for (int c = 0; c < 4; ++c) {
            const int q = 4 * w + c;
            const size_t roff = (size_t)(q * 8 + subrow) * 1024 + kb;
            gld16(pAh + roff, sm +         q * 1024);
            gld16(pAl + roff, sm + 16384 + q * 1024);
            gld16(pBh + roff, sm + 32768 + q * 1024);
            gld16(pBl + roff, sm + 49152 + q * 1024);
        }
        __syncthreads();
        #pragma unroll
        for (int kk = 0; kk < 2; ++kk) {
            const int cswz = (kk * 64 + ((l >> 4) << 4)) ^ ((l & 7) << 4);
            bf16x8 ah[4], al[4], bh[4], bl[4];
            #pragma unroll
            for (int mi = 0; mi < 4; ++mi) {
                const int off = (wm * 64 + mi * 16 + frow) * 128 + cswz;
                ah[mi] = *(const bf16x8*)(sm + off);
                al[mi] = *(const bf16x8*)(sm + 16384 + off);
            }
            #pragma unroll
            for (int ni = 0; ni < 4; ++ni) {
                const int off = (wn * 64 + ni * 16 + frow) * 128 + cswz;
                bh[ni] = *(const bf16x8*)(sm + 32768 + off);
                bl[ni] = *(const bf16x8*)(sm + 49152 + off);
            }
            #pragma unroll
            for (int mi = 0; mi < 4; ++mi)
                #pragma unroll
                for (int ni = 0; ni < 4; ++ni) {
                    acc[mi][ni] = __builtin_amdgcn_mfma_f32_16x16x32_bf16(ah[mi], bh[ni], acc[mi][ni], 0, 0, 0);
                    acc[mi][ni] = __builtin_amdgcn_mfma_f32_16x16x32_bf16(al[mi], bh[ni], acc[mi][ni], 0, 0, 0);
                    acc[mi][ni] = __builtin_amdgcn_mfma_f32_16x16x32_bf16(ah[mi], bl[ni], acc[mi][ni], 0, 0, 0);
                }
        }
        __syncthreads();
    }

    const int g = l >> 4;
    #pragma unroll
    for (int mi = 0; mi < 4; ++mi) {
        #pragma unroll
        for (int ni = 0; ni < 4; ++ni) {
            const int colg = n0 + wn * 64 + ni * 16 + frow;
            #pragma unroll
            for (int r = 0; r < 4; ++r) {
                const int rowg = m0 + wm * 64 + mi * 16 + g * 4 + r;
                const float v = acc[mi][ni][r];
                if (EPI == 0) {
                    C[(size_t)rowg * ldc + colg] = v + bias[colg];
                } else {
                    const int nb = colg >> 11, ii = colg & (W_SEQ - 1);
                    C[((size_t)(nb * OUT_CH + rowg)) * W_SEQ + ii] = v + bias[rowg];
                }
            }
        }
    }
}

// ---------------------------------------------------------------------------
// Attention: one wave per (n,h,i) row. lane = (jj = l>>1, half = l&1) for
// scores; lane = d for PV. Writes attn_out as hi/lo bf16 planes.
// ---------------------------------------------------------------------------
__global__ __launch_bounds__(256) void attn2_k(const float* __restrict__ temp,
                                               const float* __restrict__ mask,
                                               __hip_bfloat16* __restrict__ aoh,
                                               __hip_bfloat16* __restrict__ aol)
{
    const int wv = threadIdx.x >> 6, l = threadIdx.x & 63;
    const int row = blockIdx.x * 4 + wv;
    const int i = row & (W_SEQ - 1);
    const int nh = row >> 11;
    const int h = nh & (NHEAD - 1);
    const int n = nh >> 3;

    const int j0 = (i - 15 > 0) ? i - 15 : 0;
    const int j1 = (i + 15 < W_SEQ - 1) ? i + 15 : W_SEQ - 1;
    const int nj = j1 - j0 + 1;
    const int jj = l >> 1, half = l & 1;

    const float* base = temp + (size_t)(n * W_SEQ) * QKV_CH + h * 192;
    const bool act = (jj < nj);
    float s = 0.f;
    float mk = 0.f;
    if (act) {
        mk = mask[n * W_SEQ + j0 + jj];
        const float4* qp = (const float4*)(base + (size_t)i * QKV_CH + half * 32);
        const float4* kp = (const float4*)(base + (size_t)(j0 + jj) * QKV_CH + 64 + half * 32);
        #pragma unroll
        for (int d4 = 0; d4 < 8; ++d4) {
            const float4 q = qp[d4], k = kp[d4];
            s += q.x * k.x + q.y * k.y + q.z * k.z + q.w * k.w;
        }
    }
    s += __shfl_xor(s, 1);
    const bool vld = act && (mk > 0.5f);
    s = vld ? s * 0.015625f : -1.0e30f;

    float mrow = s;
    #pragma unroll
    for (int off = 2; off <= 32; off <<= 1) mrow = fmaxf(mrow, __shfl_xor(mrow, off));
    float p = vld ? expf(s - mrow) : 0.f;
    float lsum = p;
    #pragma unroll
    for (int off = 2; off <= 32; off <<= 1) lsum += __shfl_xor(lsum, off);

    float o = 0.f;
    const float* vb = base + (size_t)j0 * QKV_CH + 128;
    for (int t2 = 0; t2 < nj; ++t2) {
        const float pj = __shfl(p, 2 * t2);
        o += pj * vb[(size_t)t2 * QKV_CH + l];
    }
    o = (lsum > 0.f) ? o / lsum : 0.f;

    const size_t idx = ((size_t)(n * W_SEQ + i)) * ATTND + h * 64 + l;
    const __hip_bfloat16 hb = __float2bfloat16(o);
    aoh[idx] = hb;
    aol[idx] = __float2bfloat16(o - __bfloat162float(hb));
}

extern "C" void kernel_launch(void* const* d_in, const int* in_sizes, int n_in,
                              void* d_out, int out_size, void* d_ws, size_t ws_size,
                              hipStream_t stream)
{
    const float* input = (const float*)d_in[0];
    const float* mask  = (const float*)d_in[1];
    const float* W_in  = (const float*)d_in[2];
    const float* b_in  = (const float*)d_in[3];
    const float* W_fc  = (const float*)d_in[4];
    const float* b_fc  = (const float*)d_in[5];
    float* out = (float*)d_out;
    char* ws = (char*)d_ws;

    // workspace layout (64 MiB total, same as round-0 footprint):
    //   [0, 50331648)            temp f32 [8192][1536]   (later reused for W_fc planes)
    //   [50331648, 67108864)     W_in planes (during GEMM1), then AO planes
    float* temp = (float*)ws;
    __hip_bfloat16* AOh  = (__hip_bfloat16*)(ws + 50331648);
    __hip_bfloat16* AOl  = AOh + (size_t)8192 * ATTND;
    __hip_bfloat16* Winh = (__hip_bfloat16*)(ws + 50331648);
    __hip_bfloat16* Winl = Winh + (size_t)QKV_CH * C_IN;
    __hip_bfloat16* Wfch = (__hip_bfloat16*)ws;
    __hip_bfloat16* Wfcl = Wfch + (size_t)OUT_CH * ATTND;
    // X planes live in d_out (dead before GEMM2 overwrites it)
    __hip_bfloat16* Xh = (__hip_bfloat16*)out;
    __hip_bfloat16* Xl = Xh + (size_t)8192 * C_IN;

    prep_x_k<<<dim3(W_SEQ / 64, C_IN / 64, N_BATCH), 256, 0, stream>>>(input, Xh, Xl);
    prep_w_k<<<(QKV_CH * C_IN + 255) / 256, 256, 0, stream>>>(W_in, Winh, Winl, QKV_CH * C_IN);
    gemm_split<0><<<dim3(QKV_CH / 128, 8192 / 128), 256, 0, stream>>>(Xh, Xl, Winh, Winl, b_in, temp, QKV_CH);
    attn2_k<<<dim3(N_BATCH * NHEAD * W_SEQ / 4), 256, 0, stream>>>(temp, mask, AOh, AOl);
    prep_w_k<<<(OUT_CH * ATTND + 255) / 256, 256, 0, stream>>>(W_fc, Wfch, Wfcl, OUT_CH * ATTND);
    gemm_split<1><<<dim3(8192 / 128, OUT_CH / 128), 256, 0, stream>>>(Wfch, Wfcl, AOh, AOl, b_fc, out, 0);
}

// Round 3
// 96.475 us; speedup vs baseline: 5.2852x; 2.4030x over previous
//
#include <hip/hip_runtime.h>
#include <hip/hip_bf16.h>
#include <math.h>

#define W_SEQ   2048
#define C_IN    512
#define N_BATCH 4
#define NHEAD   8
#define QKV_CH  1536
#define OUT_CH  512
#define ATTND   512

typedef __attribute__((ext_vector_type(8))) short bf16x8;
typedef __attribute__((ext_vector_type(4))) short s16x4;
typedef __attribute__((ext_vector_type(4))) float f32x4;

__device__ __forceinline__ void gld16(const void* g, void* l) {
    __builtin_amdgcn_global_load_lds((const __attribute__((address_space(1))) void*)g,
                                     (__attribute__((address_space(3))) void*)l, 16, 0, 0);
}
__device__ __forceinline__ unsigned short f2bf(float f) {
    unsigned u = __float_as_uint(f);
    return (unsigned short)((u + 0x7FFFu + ((u >> 16) & 1u)) >> 16);
}
__device__ __forceinline__ float bf2f(unsigned short s) {
    return __uint_as_float(((unsigned)s) << 16);
}

// ---------------------------------------------------------------------------
// prep_x: input (n, c, 1, w) f32 -> Xhi/Xlo [m = n*W + i][k = c] bf16 planes
// ---------------------------------------------------------------------------
__global__ __launch_bounds__(256) void prep_x_k(const float* __restrict__ in,
                                                __hip_bfloat16* __restrict__ xh,
                                                __hip_bfloat16* __restrict__ xl)
{
    __shared__ float ts[64][65];
    const int n = blockIdx.z, i0 = blockIdx.x * 64, c0 = blockIdx.y * 64;
    const int tx = threadIdx.x & 63, ty = threadIdx.x >> 6;
    #pragma unroll
    for (int s = 0; s < 16; ++s) {
        const int c = s * 4 + ty;
        ts[c][tx] = in[((size_t)(n * C_IN + c0 + c)) * W_SEQ + i0 + tx];
    }
    __syncthreads();
    #pragma unroll
    for (int s = 0; s < 16; ++s) {
        const int i = s * 4 + ty;
        const float v = ts[tx][i];
        const __hip_bfloat16 h = __float2bfloat16(v);
        const float lo = v - __bfloat162float(h);
        const size_t idx = ((size_t)(n * W_SEQ + i0 + i)) * C_IN + c0 + tx;
        xh[idx] = h;
        xl[idx] = __float2bfloat16(lo);
    }
}

__global__ __launch_bounds__(256) void prep_w_k(const float* __restrict__ w,
                                                __hip_bfloat16* __restrict__ wh,
                                                __hip_bfloat16* __restrict__ wl, int nelem)
{
    const int idx = blockIdx.x * 256 + threadIdx.x;
    if (idx >= nelem) return;
    const float v = w[idx];
    const __hip_bfloat16 h = __float2bfloat16(v);
    wh[idx] = h;
    wl[idx] = __float2bfloat16(v - __bfloat162float(h));
}

// ---------------------------------------------------------------------------
// Split-bf16 MFMA GEMM (unchanged from round 1): C = A * B^T (+bias), K=512.
// ---------------------------------------------------------------------------
template<int EPI>
__global__ __launch_bounds__(256, 2) void gemm_split(
    const __hip_bfloat16* __restrict__ Ah, const __hip_bfloat16* __restrict__ Al,
    const __hip_bfloat16* __restrict__ Bh, const __hip_bfloat16* __restrict__ Bl,
    const float* __restrict__ bias, float* __restrict__ C, const int ldc)
{
    __shared__ __align__(16) char sm[65536];
    const int t = threadIdx.x;
    const int l = t & 63, w = t >> 6;
    const int m0 = blockIdx.y * 128, n0 = blockIdx.x * 128;
    const int wm = w >> 1, wn = w & 1;

    const int subrow = l >> 3;
    const int swz    = ((l & 7) ^ subrow) << 4;
    const char* pAh = (const char*)Ah + (size_t)m0 * 1024 + swz;
    const char* pAl = (const char*)Al + (size_t)m0 * 1024 + swz;
    const char* pBh = (const char*)Bh + (size_t)n0 * 1024 + swz;
    const char* pBl = (const char*)Bl + (size_t)n0 * 1024 + swz;

    const int frow = l & 15;
    f32x4 acc[4][4] = {};

    for (int k0 = 0; k0 < 512; k0 += 64) {
        const int kb = k0 * 2;
        #pragma unroll
        for (int c = 0; c < 4; ++c) {
            const int q = 4 * w + c;
            const size_t roff = (size_t)(q * 8 + subrow) * 1024 + kb;
            gld16(pAh + roff, sm +         q * 1024);
            gld16(pAl + roff, sm + 16384 + q * 1024);
            gld16(pBh + roff, sm + 32768 + q * 1024);
            gld16(pBl + roff, sm + 49152 + q * 1024);
        }
        __syncthreads();
        #pragma unroll
        for (int kk = 0; kk < 2; ++kk) {
            const int cswz = (kk * 64 + ((l >> 4) << 4)) ^ ((l & 7) << 4);
            bf16x8 ah[4], al[4], bh[4], bl[4];
            #pragma unroll
            for (int mi = 0; mi < 4; ++mi) {
                const int off = (wm * 64 + mi * 16 + frow) * 128 + cswz;
                ah[mi] = *(const bf16x8*)(sm + off);
                al[mi] = *(const bf16x8*)(sm + 16384 + off);
            }
            #pragma unroll
            for (int ni = 0; ni < 4; ++ni) {
                const int off = (wn * 64 + ni * 16 + frow) * 128 + cswz;
                bh[ni] = *(const bf16x8*)(sm + 32768 + off);
                bl[ni] = *(const bf16x8*)(sm + 49152 + off);
            }
            #pragma unroll
            for (int mi = 0; mi < 4; ++mi)
                #pragma unroll
                for (int ni = 0; ni < 4; ++ni) {
                    acc[mi][ni] = __builtin_amdgcn_mfma_f32_16x16x32_bf16(ah[mi], bh[ni], acc[mi][ni], 0, 0, 0);
                    acc[mi][ni] = __builtin_amdgcn_mfma_f32_16x16x32_bf16(al[mi], bh[ni], acc[mi][ni], 0, 0, 0);
                    acc[mi][ni] = __builtin_amdgcn_mfma_f32_16x16x32_bf16(ah[mi], bl[ni], acc[mi][ni], 0, 0, 0);
                }
        }
        __syncthreads();
    }

    const int g = l >> 4;
    #pragma unroll
    for (int mi = 0; mi < 4; ++mi) {
        #pragma unroll
        for (int ni = 0; ni < 4; ++ni) {
            const int colg = n0 + wn * 64 + ni * 16 + frow;
            #pragma unroll
            for (int r = 0; r < 4; ++r) {
                const int rowg = m0 + wm * 64 + mi * 16 + g * 4 + r;
                const float v = acc[mi][ni][r];
                if (EPI == 0) {
                    C[(size_t)rowg * ldc + colg] = v + bias[colg];
                } else {
                    const int nb = colg >> 11, ii = colg & (W_SEQ - 1);
                    C[((size_t)(nb * OUT_CH + rowg)) * W_SEQ + ii] = v + bias[rowg];
                }
            }
        }
    }
}

// ---------------------------------------------------------------------------
// Banded MFMA attention. Block = (i-tile of 64, h, n); 256 threads = 4 waves.
// j-window: 96 cols = [i0-16, i0+79]; band valid iff ri+1 <= jcol <= ri+31.
// Wave w owns i-rows [w*16, w*16+16).
// LDS: Khi[96][72]u16 @0, Klo @13824 (P overlays after scores:
//      Phi[64][104]u16 @0, Plo @13312), VT_hi[64][100]u16 @27648,
//      maskv f32[96] @40448. Total 40832 B -> 4 blocks/CU.
// ---------------------------------------------------------------------------
#define KLO_OFF  13824
#define PLO_OFF  13312
#define VT_OFF   27648
#define MSK_OFF  40448
#define SM_SZ    40832

__global__ __launch_bounds__(256, 3) void attn3_k(const float* __restrict__ temp,
                                                  const float* __restrict__ mask,
                                                  unsigned short* __restrict__ aoh,
                                                  unsigned short* __restrict__ aol)
{
    __shared__ __align__(16) char sm[SM_SZ];
    const int t = threadIdx.x, l = t & 63, w = t >> 6;
    const int i0 = blockIdx.x * 64, h = blockIdx.y, n = blockIdx.z;
    const int lr = l & 15, lg = l >> 4;

    const float* tbase = temp + (size_t)n * W_SEQ * QKV_CH + h * 192;

    // ---- Phase A: stage K hi/lo + V^T hi into LDS; Q into registers; mask.
    #pragma unroll
    for (int it2 = 0; it2 < 6; ++it2) {
        const int jl = w * 24 + it2 * 4 + lg;
        const int jg = i0 - 16 + jl;
        float kf[4] = {0.f, 0.f, 0.f, 0.f}, vf[4] = {0.f, 0.f, 0.f, 0.f};
        if (jg >= 0 && jg < W_SEQ) {
            const float* rp = tbase + (size_t)jg * QKV_CH;
            const float4 kv = *(const float4*)(rp + 64 + lr * 4);
            const float4 vv = *(const float4*)(rp + 128 + lr * 4);
            kf[0] = kv.x; kf[1] = kv.y; kf[2] = kv.z; kf[3] = kv.w;
            vf[0] = vv.x; vf[1] = vv.y; vf[2] = vv.z; vf[3] = vv.w;
        }
        s16x4 kh4, kl4;
        #pragma unroll
        for (int dd = 0; dd < 4; ++dd) {
            const unsigned short hb = f2bf(kf[dd]);
            kh4[dd] = (short)hb;
            kl4[dd] = (short)f2bf(kf[dd] - bf2f(hb));
        }
        *(s16x4*)(sm + jl * 144 + lr * 8)           = kh4;
        *(s16x4*)(sm + KLO_OFF + jl * 144 + lr * 8) = kl4;
        #pragma unroll
        for (int dd = 0; dd < 4; ++dd)
            *(unsigned short*)(sm + VT_OFF + (lr * 4 + dd) * 200 + jl * 2) = f2bf(vf[dd]);
    }
    // Q fragments (rows w*16+lr, k-chunk lg*8), hi/lo
    bf16x8 qhi[2], qlo[2];
    {
        const float* qrow = tbase + (size_t)(i0 + w * 16 + lr) * QKV_CH + lg * 8;
        #pragma unroll
        for (int kc = 0; kc < 2; ++kc) {
            const float4 a = *(const float4*)(qrow + kc * 32);
            const float4 b = *(const float4*)(qrow + kc * 32 + 4);
            const float qv[8] = {a.x, a.y, a.z, a.w, b.x, b.y, b.z, b.w};
            #pragma unroll
            for (int e = 0; e < 8; ++e) {
                const unsigned short hb = f2bf(qv[e]);
                qhi[kc][e] = (short)hb;
                qlo[kc][e] = (short)f2bf(qv[e] - bf2f(hb));
            }
        }
    }
    if (t < 96) {
        const int jg = i0 - 16 + t;
        const float mv = (jg >= 0 && jg < W_SEQ) ? mask[n * W_SEQ + jg] : 0.f;
        *(float*)(sm + MSK_OFF + t * 4) = mv;
    }
    __syncthreads();

    // ---- Phase B: S = Q K^T (3-term split), C-frags in registers.
    f32x4 sacc[6] = {};
    #pragma unroll
    for (int nf = 0; nf < 6; ++nf) {
        #pragma unroll
        for (int kk = 0; kk < 2; ++kk) {
            const int ko = kk * 64 + lg * 16;
            const bf16x8 kh = *(const bf16x8*)(sm + (nf * 16 + lr) * 144 + ko);
            const bf16x8 kl = *(const bf16x8*)(sm + KLO_OFF + (nf * 16 + lr) * 144 + ko);
            sacc[nf] = __builtin_amdgcn_mfma_f32_16x16x32_bf16(qhi[kk], kh, sacc[nf], 0, 0, 0);
            sacc[nf] = __builtin_amdgcn_mfma_f32_16x16x32_bf16(qlo[kk], kh, sacc[nf], 0, 0, 0);
            sacc[nf] = __builtin_amdgcn_mfma_f32_16x16x32_bf16(qhi[kk], kl, sacc[nf], 0, 0, 0);
        }
    }
    __syncthreads();   // all waves done reading K before P overlays it

    // ---- Phase C: masked softmax per row; write normalized P hi/lo to LDS.
    float mv[6];
    #pragma unroll
    for (int nf = 0; nf < 6; ++nf)
        mv[nf] = *(const float*)(sm + MSK_OFF + (nf * 16 + lr) * 4);

    #pragma unroll
    for (int r = 0; r < 4; ++r) {
        const int ri = w * 16 + lg * 4 + r;     // i-local (0..63)
        float sv[6], mrow = -1.0e30f;
        #pragma unroll
        for (int nf = 0; nf < 6; ++nf) {
            const int jcol = nf * 16 + lr;
            const bool valid = (jcol > ri) && (jcol <= ri + 31) && (mv[nf] > 0.5f);
            const float s = valid ? sacc[nf][r] * 0.015625f : -1.0e30f;
            sv[nf] = s;
            mrow = fmaxf(mrow, s);
        }
        #pragma unroll
        for (int off = 1; off <= 8; off <<= 1) mrow = fmaxf(mrow, __shfl_xor(mrow, off));
        float ls = 0.f;
        #pragma unroll
        for (int nf = 0; nf < 6; ++nf) {
            float pp = __expf(sv[nf] - mrow);
            pp = (sv[nf] > -1.0e29f) ? pp : 0.f;
            sv[nf] = pp;
            ls += pp;
        }
        #pragma unroll
        for (int off = 1; off <= 8; off <<= 1) ls += __shfl_xor(ls, off);
        const float rinv = (ls > 0.f) ? 1.f / ls : 0.f;
        #pragma unroll
        for (int nf = 0; nf < 6; ++nf) {
            const int jcol = nf * 16 + lr;
            const float pn = sv[nf] * rinv;
            const unsigned short ph = f2bf(pn);
            *(unsigned short*)(sm + ri * 208 + jcol * 2)           = ph;
            *(unsigned short*)(sm + PLO_OFF + ri * 208 + jcol * 2) = f2bf(pn - bf2f(ph));
        }
    }

    // ---- Phase D: O = P V (P hi/lo x V hi), intra-wave LDS dependency only.
    f32x4 oacc[4] = {};
    #pragma unroll
    for (int ks = 0; ks < 3; ++ks) {
        const int po = (w * 16 + lr) * 208 + ks * 64 + lg * 16;
        const bf16x8 pah = *(const bf16x8*)(sm + po);
        const bf16x8 pal = *(const bf16x8*)(sm + PLO_OFF + po);
        #pragma unroll
        for (int nf2 = 0; nf2 < 4; ++nf2) {
            const char* vp = sm + VT_OFF + (nf2 * 16 + lr) * 200 + ks * 64 + lg * 16;
            const s16x4 v0 = *(const s16x4*)(vp);
            const s16x4 v1 = *(const s16x4*)(vp + 8);
            bf16x8 vb;
            #pragma unroll
            for (int e = 0; e < 4; ++e) { vb[e] = v0[e]; vb[e + 4] = v1[e]; }
            oacc[nf2] = __builtin_amdgcn_mfma_f32_16x16x32_bf16(pah, vb, oacc[nf2], 0, 0, 0);
            oacc[nf2] = __builtin_amdgcn_mfma_f32_16x16x32_bf16(pal, vb, oacc[nf2], 0, 0, 0);
        }
    }

    // ---- Epilogue: store attn-out hi/lo bf16 planes.
    #pragma unroll
    for (int nf2 = 0; nf2 < 4; ++nf2) {
        #pragma unroll
        for (int r = 0; r < 4; ++r) {
            const float o = oacc[nf2][r];
            const int ri = w * 16 + lg * 4 + r;
            const size_t idx = ((size_t)(n * W_SEQ + i0 + ri)) * ATTND + h * 64 + nf2 * 16 + lr;
            const unsigned short hb = f2bf(o);
            aoh[idx] = hb;
            aol[idx] = f2bf(o - bf2f(hb));
        }
    }
}

extern "C" void kernel_launch(void* const* d_in, const int* in_sizes, int n_in,
                              void* d_out, int out_size, void* d_ws, size_t ws_size,
                              hipStream_t stream)
{
    const float* input = (const float*)d_in[0];
    const float* mask  = (const float*)d_in[1];
    const float* W_in  = (const float*)d_in[2];
    const float* b_in  = (const float*)d_in[3];
    const float* W_fc  = (const float*)d_in[4];
    const float* b_fc  = (const float*)d_in[5];
    float* out = (float*)d_out;
    char* ws = (char*)d_ws;

    float* temp = (float*)ws;                                  // 8192*1536 f32
    __hip_bfloat16* AOh  = (__hip_bfloat16*)(ws + 50331648);
    __hip_bfloat16* AOl  = AOh + (size_t)8192 * ATTND;
    __hip_bfloat16* Winh = (__hip_bfloat16*)(ws + 50331648);
    __hip_bfloat16* Winl = Winh + (size_t)QKV_CH * C_IN;
    __hip_bfloat16* Wfch = (__hip_bfloat16*)ws;
    __hip_bfloat16* Wfcl = Wfch + (size_t)OUT_CH * ATTND;
    __hip_bfloat16* Xh = (__hip_bfloat16*)out;
    __hip_bfloat16* Xl = Xh + (size_t)8192 * C_IN;

    prep_x_k<<<dim3(W_SEQ / 64, C_IN / 64, N_BATCH), 256, 0, stream>>>(input, Xh, Xl);
    prep_w_k<<<(QKV_CH * C_IN + 255) / 256, 256, 0, stream>>>(W_in, Winh, Winl, QKV_CH * C_IN);
    gemm_split<0><<<dim3(QKV_CH / 128, 8192 / 128), 256, 0, stream>>>(Xh, Xl, Winh, Winl, b_in, temp, QKV_CH);
    attn3_k<<<dim3(W_SEQ / 64, NHEAD, N_BATCH), 256, 0, stream>>>(temp, mask,
                                                                  (unsigned short*)AOh, (unsigned short*)AOl);
    prep_w_k<<<(OUT_CH * ATTND + 255) / 256, 256, 0, stream>>>(W_fc, Wfch, Wfcl, OUT_CH * ATTND);
    gemm_split<1><<<dim3(8192 / 128, OUT_CH / 128), 256, 0, stream>>>(Wfch, Wfcl, AOh, AOl, b_fc, out, 0);
}

// Round 5
// 82.424 us; speedup vs baseline: 6.1861x; 1.1705x over previous
//
#include <hip/hip_runtime.h>
#include <hip/hip_bf16.h>
#include <math.h>

#define W_SEQ   2048
#define C_IN    512
#define N_BATCH 4
#define NHEAD   8
#define QKV_CH  1536
#define OUT_CH  512
#define ATTND   512

typedef __attribute__((ext_vector_type(8))) short bf16x8;
typedef __attribute__((ext_vector_type(4))) short s16x4;
typedef __attribute__((ext_vector_type(4))) float f32x4;

__device__ __forceinline__ void gld16(const void* g, void* l) {
    __builtin_amdgcn_global_load_lds((const __attribute__((address_space(1))) void*)g,
                                     (__attribute__((address_space(3))) void*)l, 16, 0, 0);
}
__device__ __forceinline__ unsigned short f2bf(float f) {
    unsigned u = __float_as_uint(f);
    return (unsigned short)((u + 0x7FFFu + ((u >> 16) & 1u)) >> 16);
}
__device__ __forceinline__ float bf2f(unsigned short s) {
    return __uint_as_float(((unsigned)s) << 16);
}

// ---------------------------------------------------------------------------
// prep_x: input (n, c, 1, w) f32 -> Xhi/Xlo [m = n*W + i][k = c] bf16 planes
// ---------------------------------------------------------------------------
__global__ __launch_bounds__(256) void prep_x_k(const float* __restrict__ in,
                                                __hip_bfloat16* __restrict__ xh,
                                                __hip_bfloat16* __restrict__ xl)
{
    __shared__ float ts[64][65];
    const int n = blockIdx.z, i0 = blockIdx.x * 64, c0 = blockIdx.y * 64;
    const int tx = threadIdx.x & 63, ty = threadIdx.x >> 6;
    #pragma unroll
    for (int s = 0; s < 16; ++s) {
        const int c = s * 4 + ty;
        ts[c][tx] = in[((size_t)(n * C_IN + c0 + c)) * W_SEQ + i0 + tx];
    }
    __syncthreads();
    #pragma unroll
    for (int s = 0; s < 16; ++s) {
        const int i = s * 4 + ty;
        const float v = ts[tx][i];
        const __hip_bfloat16 h = __float2bfloat16(v);
        const float lo = v - __bfloat162float(h);
        const size_t idx = ((size_t)(n * W_SEQ + i0 + i)) * C_IN + c0 + tx;
        xh[idx] = h;
        xl[idx] = __float2bfloat16(lo);
    }
}

// ---------------------------------------------------------------------------
// prep_w2: W_in -> hi/lo planes;  W_fc -> hi plane only. One launch.
// ---------------------------------------------------------------------------
__global__ __launch_bounds__(256) void prep_w2_k(const float* __restrict__ w1,
                                                 __hip_bfloat16* __restrict__ w1h,
                                                 __hip_bfloat16* __restrict__ w1l, int n1,
                                                 const float* __restrict__ w2,
                                                 __hip_bfloat16* __restrict__ w2h, int n2)
{
    const int idx = blockIdx.x * 256 + threadIdx.x;
    if (idx < n1) {
        const float v = w1[idx];
        const __hip_bfloat16 h = __float2bfloat16(v);
        w1h[idx] = h;
        w1l[idx] = __float2bfloat16(v - __bfloat162float(h));
    } else if (idx < n1 + n2) {
        const int j = idx - n1;
        w2h[j] = __float2bfloat16(w2[j]);
    }
}

// ---------------------------------------------------------------------------
// MFMA GEMM: C = A * B^T (+bias), K = 512 fixed.
// TERMS==3: split-bf16 (Ahi*Bhi + Alo*Bhi + Ahi*Blo), 64 KB LDS, 2 blk/CU.
// TERMS==1: plain bf16 (hi planes only),              32 KB LDS, 4 blk/CU.
// EPI 0: C[row*ldc + col] = acc + bias[col]
// EPI 1: C[((col>>11)*512 + row)*2048 + (col&2047)] = acc + bias[row]
// ---------------------------------------------------------------------------
template<int EPI, int TERMS>
__global__ __launch_bounds__(256, (TERMS == 3) ? 2 : 4) void gemm_split(
    const __hip_bfloat16* __restrict__ Ah, const __hip_bfloat16* __restrict__ Al,
    const __hip_bfloat16* __restrict__ Bh, const __hip_bfloat16* __restrict__ Bl,
    const float* __restrict__ bias, float* __restrict__ C, const int ldc)
{
    constexpr int SMSZ  = (TERMS == 3) ? 65536 : 32768;
    constexpr int BH_OFF = (TERMS == 3) ? 32768 : 16384;
    __shared__ __align__(16) char sm[SMSZ];
    const int t = threadIdx.x;
    const int l = t & 63, w = t >> 6;
    const int m0 = blockIdx.y * 128, n0 = blockIdx.x * 128;
    const int wm = w >> 1, wn = w & 1;

    const int subrow = l >> 3;
    const int swz    = ((l & 7) ^ subrow) << 4;
    const char* pAh = (const char*)Ah + (size_t)m0 * 1024 + swz;
    const char* pAl = (const char*)Al + (size_t)m0 * 1024 + swz;
    const char* pBh = (const char*)Bh + (size_t)n0 * 1024 + swz;
    const char* pBl = (const char*)Bl + (size_t)n0 * 1024 + swz;

    const int frow = l & 15;
    f32x4 acc[4][4] = {};

    for (int k0 = 0; k0 < 512; k0 += 64) {
        const int kb = k0 * 2;
        #pragma unroll
        for (int c = 0; c < 4; ++c) {
            const int q = 4 * w + c;
            const size_t roff = (size_t)(q * 8 + subrow) * 1024 + kb;
            gld16(pAh + roff, sm + q * 1024);
            gld16(pBh + roff, sm + BH_OFF + q * 1024);
            if (TERMS == 3) {
                gld16(pAl + roff, sm + 16384 + q * 1024);
                gld16(pBl + roff, sm + 49152 + q * 1024);
            }
        }
        __syncthreads();
        #pragma unroll
        for (int kk = 0; kk < 2; ++kk) {
            const int cswz = (kk * 64 + ((l >> 4) << 4)) ^ ((l & 7) << 4);
            bf16x8 ah[4], al[4], bh[4], bl[4];
            #pragma unroll
            for (int mi = 0; mi < 4; ++mi) {
                const int off = (wm * 64 + mi * 16 + frow) * 128 + cswz;
                ah[mi] = *(const bf16x8*)(sm + off);
                if (TERMS == 3) al[mi] = *(const bf16x8*)(sm + 16384 + off);
            }
            #pragma unroll
            for (int ni = 0; ni < 4; ++ni) {
                const int off = (wn * 64 + ni * 16 + frow) * 128 + cswz;
                bh[ni] = *(const bf16x8*)(sm + BH_OFF + off);
                if (TERMS == 3) bl[ni] = *(const bf16x8*)(sm + 49152 + off);
            }
            #pragma unroll
            for (int mi = 0; mi < 4; ++mi)
                #pragma unroll
                for (int ni = 0; ni < 4; ++ni) {
                    acc[mi][ni] = __builtin_amdgcn_mfma_f32_16x16x32_bf16(ah[mi], bh[ni], acc[mi][ni], 0, 0, 0);
                    if (TERMS == 3) {
                        acc[mi][ni] = __builtin_amdgcn_mfma_f32_16x16x32_bf16(al[mi], bh[ni], acc[mi][ni], 0, 0, 0);
                        acc[mi][ni] = __builtin_amdgcn_mfma_f32_16x16x32_bf16(ah[mi], bl[ni], acc[mi][ni], 0, 0, 0);
                    }
                }
        }
        __syncthreads();
    }

    const int g = l >> 4;
    #pragma unroll
    for (int mi = 0; mi < 4; ++mi) {
        #pragma unroll
        for (int ni = 0; ni < 4; ++ni) {
            const int colg = n0 + wn * 64 + ni * 16 + frow;
            #pragma unroll
            for (int r = 0; r < 4; ++r) {
                const int rowg = m0 + wm * 64 + mi * 16 + g * 4 + r;
                const float v = acc[mi][ni][r];
                if (EPI == 0) {
                    C[(size_t)rowg * ldc + colg] = v + bias[colg];
                } else {
                    const int nb = colg >> 11, ii = colg & (W_SEQ - 1);
                    C[((size_t)(nb * OUT_CH + rowg)) * W_SEQ + ii] = v + bias[rowg];
                }
            }
        }
    }
}

// ---------------------------------------------------------------------------
// Banded MFMA attention (writes only the hi AO plane).
// ---------------------------------------------------------------------------
#define KLO_OFF  13824
#define PLO_OFF  13312
#define VT_OFF   27648
#define MSK_OFF  40448
#define SM_SZ    40832

__global__ __launch_bounds__(256, 3) void attn3_k(const float* __restrict__ temp,
                                                  const float* __restrict__ mask,
                                                  unsigned short* __restrict__ aoh)
{
    __shared__ __align__(16) char sm[SM_SZ];
    const int t = threadIdx.x, l = t & 63, w = t >> 6;
    const int i0 = blockIdx.x * 64, h = blockIdx.y, n = blockIdx.z;
    const int lr = l & 15, lg = l >> 4;

    const float* tbase = temp + (size_t)n * W_SEQ * QKV_CH + h * 192;

    #pragma unroll
    for (int it2 = 0; it2 < 6; ++it2) {
        const int jl = w * 24 + it2 * 4 + lg;
        const int jg = i0 - 16 + jl;
        float kf[4] = {0.f, 0.f, 0.f, 0.f}, vf[4] = {0.f, 0.f, 0.f, 0.f};
        if (jg >= 0 && jg < W_SEQ) {
            const float* rp = tbase + (size_t)jg * QKV_CH;
            const float4 kv = *(const float4*)(rp + 64 + lr * 4);
            const float4 vv = *(const float4*)(rp + 128 + lr * 4);
            kf[0] = kv.x; kf[1] = kv.y; kf[2] = kv.z; kf[3] = kv.w;
            vf[0] = vv.x; vf[1] = vv.y; vf[2] = vv.z; vf[3] = vv.w;
        }
        s16x4 kh4, kl4;
        #pragma unroll
        for (int dd = 0; dd < 4; ++dd) {
            const unsigned short hb = f2bf(kf[dd]);
            kh4[dd] = (short)hb;
            kl4[dd] = (short)f2bf(kf[dd] - bf2f(hb));
        }
        *(s16x4*)(sm + jl * 144 + lr * 8)           = kh4;
        *(s16x4*)(sm + KLO_OFF + jl * 144 + lr * 8) = kl4;
        #pragma unroll
        for (int dd = 0; dd < 4; ++dd)
            *(unsigned short*)(sm + VT_OFF + (lr * 4 + dd) * 200 + jl * 2) = f2bf(vf[dd]);
    }
    bf16x8 qhi[2], qlo[2];
    {
        const float* qrow = tbase + (size_t)(i0 + w * 16 + lr) * QKV_CH + lg * 8;
        #pragma unroll
        for (int kc = 0; kc < 2; ++kc) {
            const float4 a = *(const float4*)(qrow + kc * 32);
            const float4 b = *(const float4*)(qrow + kc * 32 + 4);
            const float qv[8] = {a.x, a.y, a.z, a.w, b.x, b.y, b.z, b.w};
            #pragma unroll
            for (int e = 0; e < 8; ++e) {
                const unsigned short hb = f2bf(qv[e]);
                qhi[kc][e] = (short)hb;
                qlo[kc][e] = (short)f2bf(qv[e] - bf2f(hb));
            }
        }
    }
    if (t < 96) {
        const int jg = i0 - 16 + t;
        const float mv = (jg >= 0 && jg < W_SEQ) ? mask[n * W_SEQ + jg] : 0.f;
        *(float*)(sm + MSK_OFF + t * 4) = mv;
    }
    __syncthreads();

    f32x4 sacc[6] = {};
    #pragma unroll
    for (int nf = 0; nf < 6; ++nf) {
        #pragma unroll
        for (int kk = 0; kk < 2; ++kk) {
            const int ko = kk * 64 + lg * 16;
            const bf16x8 kh = *(const bf16x8*)(sm + (nf * 16 + lr) * 144 + ko);
            const bf16x8 kl = *(const bf16x8*)(sm + KLO_OFF + (nf * 16 + lr) * 144 + ko);
            sacc[nf] = __builtin_amdgcn_mfma_f32_16x16x32_bf16(qhi[kk], kh, sacc[nf], 0, 0, 0);
            sacc[nf] = __builtin_amdgcn_mfma_f32_16x16x32_bf16(qlo[kk], kh, sacc[nf], 0, 0, 0);
            sacc[nf] = __builtin_amdgcn_mfma_f32_16x16x32_bf16(qhi[kk], kl, sacc[nf], 0, 0, 0);
        }
    }
    __syncthreads();

    float mv[6];
    #pragma unroll
    for (int nf = 0; nf < 6; ++nf)
        mv[nf] = *(const float*)(sm + MSK_OFF + (nf * 16 + lr) * 4);

    #pragma unroll
    for (int r = 0; r < 4; ++r) {
        const int ri = w * 16 + lg * 4 + r;
        float sv[6], mrow = -1.0e30f;
        #pragma unroll
        for (int nf = 0; nf < 6; ++nf) {
            const int jcol = nf * 16 + lr;
            const bool valid = (jcol > ri) && (jcol <= ri + 31) && (mv[nf] > 0.5f);
            const float s = valid ? sacc[nf][r] * 0.015625f : -1.0e30f;
            sv[nf] = s;
            mrow = fmaxf(mrow, s);
        }
        #pragma unroll
        for (int off = 1; off <= 8; off <<= 1) mrow = fmaxf(mrow, __shfl_xor(mrow, off));
        float ls = 0.f;
        #pragma unroll
        for (int nf = 0; nf < 6; ++nf) {
            float pp = __expf(sv[nf] - mrow);
            pp = (sv[nf] > -1.0e29f) ? pp : 0.f;
            sv[nf] = pp;
            ls += pp;
        }
        #pragma unroll
        for (int off = 1; off <= 8; off <<= 1) ls += __shfl_xor(ls, off);
        const float rinv = (ls > 0.f) ? 1.f / ls : 0.f;
        #pragma unroll
        for (int nf = 0; nf < 6; ++nf) {
            const int jcol = nf * 16 + lr;
            const float pn = sv[nf] * rinv;
            const unsigned short ph = f2bf(pn);
            *(unsigned short*)(sm + ri * 208 + jcol * 2)           = ph;
            *(unsigned short*)(sm + PLO_OFF + ri * 208 + jcol * 2) = f2bf(pn - bf2f(ph));
        }
    }

    f32x4 oacc[4] = {};
    #pragma unroll
    for (int ks = 0; ks < 3; ++ks) {
        const int po = (w * 16 + lr) * 208 + ks * 64 + lg * 16;
        const bf16x8 pah = *(const bf16x8*)(sm + po);
        const bf16x8 pal = *(const bf16x8*)(sm + PLO_OFF + po);
        #pragma unroll
        for (int nf2 = 0; nf2 < 4; ++nf2) {
            const char* vp = sm + VT_OFF + (nf2 * 16 + lr) * 200 + ks * 64 + lg * 16;
            const s16x4 v0 = *(const s16x4*)(vp);
            const s16x4 v1 = *(const s16x4*)(vp + 8);
            bf16x8 vb;
            #pragma unroll
            for (int e = 0; e < 4; ++e) { vb[e] = v0[e]; vb[e + 4] = v1[e]; }
            oacc[nf2] = __builtin_amdgcn_mfma_f32_16x16x32_bf16(pah, vb, oacc[nf2], 0, 0, 0);
            oacc[nf2] = __builtin_amdgcn_mfma_f32_16x16x32_bf16(pal, vb, oacc[nf2], 0, 0, 0);
        }
    }

    #pragma unroll
    for (int nf2 = 0; nf2 < 4; ++nf2) {
        #pragma unroll
        for (int r = 0; r < 4; ++r) {
            const float o = oacc[nf2][r];
            const int ri = w * 16 + lg * 4 + r;
            const size_t idx = ((size_t)(n * W_SEQ + i0 + ri)) * ATTND + h * 64 + nf2 * 16 + lr;
            aoh[idx] = f2bf(o);
        }
    }
}

extern "C" void kernel_launch(void* const* d_in, const int* in_sizes, int n_in,
                              void* d_out, int out_size, void* d_ws, size_t ws_size,
                              hipStream_t stream)
{
    const float* input = (const float*)d_in[0];
    const float* mask  = (const float*)d_in[1];
    const float* W_in  = (const float*)d_in[2];
    const float* b_in  = (const float*)d_in[3];
    const float* W_fc  = (const float*)d_in[4];
    const float* b_fc  = (const float*)d_in[5];
    float* out = (float*)d_out;
    char* ws = (char*)d_ws;

    // Disjoint workspace layout (total 62390272 B < 64 MiB, proven-safe size):
    //   temp  [0,        50331648)  f32[8192][1536]
    //   AOh   [50331648, 58720256)  bf16[8192][512]
    //   Winh  [58720256, 60293120)  bf16[1536][512]
    //   Winl  [60293120, 61865984)  bf16[1536][512]
    //   Wfch  [61865984, 62390272)  bf16[512][512]
    float* temp = (float*)ws;
    __hip_bfloat16* AOh  = (__hip_bfloat16*)(ws + 50331648);
    __hip_bfloat16* Winh = (__hip_bfloat16*)(ws + 58720256);
    __hip_bfloat16* Winl = (__hip_bfloat16*)(ws + 60293120);
    __hip_bfloat16* Wfch = (__hip_bfloat16*)(ws + 61865984);
    // X planes live in d_out (dead before GEMM2 overwrites it)
    __hip_bfloat16* Xh = (__hip_bfloat16*)out;
    __hip_bfloat16* Xl = Xh + (size_t)8192 * C_IN;

    prep_x_k<<<dim3(W_SEQ / 64, C_IN / 64, N_BATCH), 256, 0, stream>>>(input, Xh, Xl);
    prep_w2_k<<<(QKV_CH * C_IN + OUT_CH * ATTND + 255) / 256, 256, 0, stream>>>(
        W_in, Winh, Winl, QKV_CH * C_IN, W_fc, Wfch, OUT_CH * ATTND);
    // GEMM1 qk-part: channels [0,1024), plain bf16
    gemm_split<0, 1><<<dim3(1024 / 128, 8192 / 128), 256, 0, stream>>>(
        Xh, Xh, Winh, Winh, b_in, temp, QKV_CH);
    // GEMM1 v-part: channels [1024,1536), 3-term split
    gemm_split<0, 3><<<dim3(512 / 128, 8192 / 128), 256, 0, stream>>>(
        Xh, Xl, Winh + (size_t)1024 * C_IN, Winl + (size_t)1024 * C_IN,
        b_in + 1024, temp + 1024, QKV_CH);
    attn3_k<<<dim3(W_SEQ / 64, NHEAD, N_BATCH), 256, 0, stream>>>(temp, mask, (unsigned short*)AOh);
    // GEMM2: plain bf16
    gemm_split<1, 1><<<dim3(8192 / 128, OUT_CH / 128), 256, 0, stream>>>(
        Wfch, Wfch, AOh, AOh, b_fc, out, 0);
}

// Round 6
// 57.459 us; speedup vs baseline: 8.8738x; 1.4345x over previous
//
#include <hip/hip_runtime.h>
#include <hip/hip_bf16.h>
#include <math.h>

#define W_SEQ   2048
#define C_IN    512
#define N_BATCH 4
#define NHEAD   8
#define QKV_CH  1536
#define OUT_CH  512
#define ATTND   512

typedef __attribute__((ext_vector_type(8))) short bf16x8;
typedef __attribute__((ext_vector_type(4))) float f32x4;

__device__ __forceinline__ void gld16(const void* g, void* l) {
    __builtin_amdgcn_global_load_lds((const __attribute__((address_space(1))) void*)g,
                                     (__attribute__((address_space(3))) void*)l, 16, 0, 0);
}
__device__ __forceinline__ unsigned short f2bf(float f) {
    unsigned u = __float_as_uint(f);
    return (unsigned short)((u + 0x7FFFu + ((u >> 16) & 1u)) >> 16);
}

// ---------------------------------------------------------------------------
// prep_x: input (n, c, 1, w) f32 -> Xh [m = n*W + i][k = c] bf16 (hi only)
// ---------------------------------------------------------------------------
__global__ __launch_bounds__(256) void prep_x_k(const float* __restrict__ in,
                                                unsigned short* __restrict__ xh)
{
    __shared__ float ts[64][65];
    const int n = blockIdx.z, i0 = blockIdx.x * 64, c0 = blockIdx.y * 64;
    const int tx = threadIdx.x & 63, ty = threadIdx.x >> 6;
    #pragma unroll
    for (int s = 0; s < 16; ++s) {
        const int c = s * 4 + ty;
        ts[c][tx] = in[((size_t)(n * C_IN + c0 + c)) * W_SEQ + i0 + tx];
    }
    __syncthreads();
    #pragma unroll
    for (int s = 0; s < 16; ++s) {
        const int i = s * 4 + ty;
        xh[((size_t)(n * W_SEQ + i0 + i)) * C_IN + c0 + tx] = f2bf(ts[tx][i]);
    }
}

// ---------------------------------------------------------------------------
// prep_w: W_in -> bf16, W_fc -> bf16 (hi planes only), float4-vectorized.
// ---------------------------------------------------------------------------
__global__ __launch_bounds__(256) void prep_w_k(const float* __restrict__ w1,
                                                unsigned short* __restrict__ w1h, int n1_4,
                                                const float* __restrict__ w2,
                                                unsigned short* __restrict__ w2h, int n2_4)
{
    const int idx = blockIdx.x * 256 + threadIdx.x;
    if (idx < n1_4) {
        const float4 v = ((const float4*)w1)[idx];
        ushort4 h; h.x = f2bf(v.x); h.y = f2bf(v.y); h.z = f2bf(v.z); h.w = f2bf(v.w);
        ((ushort4*)w1h)[idx] = h;
    } else if (idx < n1_4 + n2_4) {
        const int j = idx - n1_4;
        const float4 v = ((const float4*)w2)[j];
        ushort4 h; h.x = f2bf(v.x); h.y = f2bf(v.y); h.z = f2bf(v.z); h.w = f2bf(v.w);
        ((ushort4*)w2h)[j] = h;
    }
}

// ---------------------------------------------------------------------------
// 1-term bf16 MFMA GEMM: C = A * B^T (+bias), K = 512 fixed. 32 KB LDS.
// EPI 0: bf16 store C[row*ldc + col] = acc + bias[col]      (GEMM1 -> QKVh)
// EPI 1: f32 store out[((col>>11)*512 + row)*2048 + (col&2047)] = acc+bias[row]
// ---------------------------------------------------------------------------
template<int EPI>
__global__ __launch_bounds__(256, 4) void gemm_bf16(
    const unsigned short* __restrict__ A, const unsigned short* __restrict__ B,
    const float* __restrict__ bias, void* __restrict__ Cv, const int ldc)
{
    __shared__ __align__(16) char sm[32768];
    const int t = threadIdx.x;
    const int l = t & 63, w = t >> 6;
    const int m0 = blockIdx.y * 128, n0 = blockIdx.x * 128;
    const int wm = w >> 1, wn = w & 1;

    const int subrow = l >> 3;
    const int swz    = ((l & 7) ^ subrow) << 4;
    const char* pA = (const char*)A + (size_t)m0 * 1024 + swz;
    const char* pB = (const char*)B + (size_t)n0 * 1024 + swz;

    const int frow = l & 15;
    f32x4 acc[4][4] = {};

    for (int k0 = 0; k0 < 512; k0 += 64) {
        const int kb = k0 * 2;
        #pragma unroll
        for (int c = 0; c < 4; ++c) {
            const int q = 4 * w + c;
            const size_t roff = (size_t)(q * 8 + subrow) * 1024 + kb;
            gld16(pA + roff, sm +         q * 1024);
            gld16(pB + roff, sm + 16384 + q * 1024);
        }
        __syncthreads();
        #pragma unroll
        for (int kk = 0; kk < 2; ++kk) {
            const int cswz = (kk * 64 + ((l >> 4) << 4)) ^ ((l & 7) << 4);
            bf16x8 a[4], b[4];
            #pragma unroll
            for (int mi = 0; mi < 4; ++mi)
                a[mi] = *(const bf16x8*)(sm + (wm * 64 + mi * 16 + frow) * 128 + cswz);
            #pragma unroll
            for (int ni = 0; ni < 4; ++ni)
                b[ni] = *(const bf16x8*)(sm + 16384 + (wn * 64 + ni * 16 + frow) * 128 + cswz);
            #pragma unroll
            for (int mi = 0; mi < 4; ++mi)
                #pragma unroll
                for (int ni = 0; ni < 4; ++ni)
                    acc[mi][ni] = __builtin_amdgcn_mfma_f32_16x16x32_bf16(a[mi], b[ni], acc[mi][ni], 0, 0, 0);
        }
        __syncthreads();
    }

    const int g = l >> 4;
    #pragma unroll
    for (int mi = 0; mi < 4; ++mi) {
        #pragma unroll
        for (int ni = 0; ni < 4; ++ni) {
            const int colg = n0 + wn * 64 + ni * 16 + frow;
            #pragma unroll
            for (int r = 0; r < 4; ++r) {
                const int rowg = m0 + wm * 64 + mi * 16 + g * 4 + r;
                const float v = acc[mi][ni][r];
                if (EPI == 0) {
                    ((unsigned short*)Cv)[(size_t)rowg * ldc + colg] = f2bf(v + bias[colg]);
                } else {
                    const int nb = colg >> 11, ii = colg & (W_SEQ - 1);
                    ((float*)Cv)[((size_t)(nb * OUT_CH + rowg)) * W_SEQ + ii] = v + bias[rowg];
                }
            }
        }
    }
}

// ---------------------------------------------------------------------------
// Banded MFMA attention, all-bf16. Block = (i-tile 64, h, n); 4 waves.
// j-window 96 = [i0-16, i0+79]; band valid iff ri+1 <= jcol <= ri+31.
// QKVh layout: [n][i][1536] bf16, channel = h*192 + {0:q, 64:k, 128:v} + d.
// LDS: K[96][144B] @0 (P[64][208B] overlays after B), VT[64][256B] @13824
//      (chunk-XOR swizzled by (d>>3)^(d&7)), mask f32[96] @30208. 30592 B.
// ---------------------------------------------------------------------------
#define VT_OFF  13824
#define MSK_OFF 30208
#define SM_SZ   30592

__global__ __launch_bounds__(256, 4) void attn4_k(const unsigned short* __restrict__ qkv,
                                                  const float* __restrict__ mask,
                                                  unsigned short* __restrict__ aoh)
{
    __shared__ __align__(16) char sm[SM_SZ];
    const int t = threadIdx.x, l = t & 63, w = t >> 6;
    const int i0 = blockIdx.x * 64, h = blockIdx.y, n = blockIdx.z;
    const int lr = l & 15, lg = l >> 4;

    const char* tb = (const char*)qkv + ((size_t)n * W_SEQ * QKV_CH + h * 192) * 2;

    // ---- Phase A: stage K rows + swizzled V^T; Q into fragments; mask.
    const int r8 = l >> 3, c8 = l & 7;
    #pragma unroll
    for (int it = 0; it < 3; ++it) {
        const int jl = w * 24 + it * 8 + r8;
        const int jg = i0 - 16 + jl;
        bf16x8 kv = {}, vv = {};
        if (jg >= 0 && jg < W_SEQ) {
            const char* rp = tb + (size_t)jg * 3072;
            kv = *(const bf16x8*)(rp + 128 + c8 * 16);
            vv = *(const bf16x8*)(rp + 256 + c8 * 16);
        }
        *(bf16x8*)(sm + jl * 144 + c8 * 16) = kv;
        const int J0 = jl >> 3;            // j-chunk (const per iter)
        #pragma unroll
        for (int e = 0; e < 8; ++e) {
            const int d = c8 * 8 + e;
            const int fold = ((d >> 3) ^ d) & 7;
            *(unsigned short*)(sm + VT_OFF + d * 256 + (((J0 ^ fold) << 4) | ((jl & 7) * 2)))
                = (unsigned short)vv[e];
        }
    }
    bf16x8 qh[2];
    {
        const char* qrow = tb + (size_t)(i0 + w * 16 + lr) * 3072 + lg * 16;
        qh[0] = *(const bf16x8*)(qrow);
        qh[1] = *(const bf16x8*)(qrow + 64);
    }
    if (t < 96) {
        const int jg = i0 - 16 + t;
        *(float*)(sm + MSK_OFF + t * 4) = (jg >= 0 && jg < W_SEQ) ? mask[n * W_SEQ + jg] : 0.f;
    }
    __syncthreads();

    // ---- Phase B: S = Q K^T (1-term).
    f32x4 sacc[6] = {};
    #pragma unroll
    for (int nf = 0; nf < 6; ++nf) {
        #pragma unroll
        for (int kk = 0; kk < 2; ++kk) {
            const bf16x8 kh = *(const bf16x8*)(sm + (nf * 16 + lr) * 144 + kk * 64 + lg * 16);
            sacc[nf] = __builtin_amdgcn_mfma_f32_16x16x32_bf16(qh[kk], kh, sacc[nf], 0, 0, 0);
        }
    }
    __syncthreads();   // all waves done with K before P overlays it

    // ---- Phase C: masked softmax per row; normalized P (bf16) into LDS.
    float mv[6];
    #pragma unroll
    for (int nf = 0; nf < 6; ++nf)
        mv[nf] = *(const float*)(sm + MSK_OFF + (nf * 16 + lr) * 4);

    #pragma unroll
    for (int r = 0; r < 4; ++r) {
        const int ri = w * 16 + lg * 4 + r;
        float sv[6], mrow = -1.0e30f;
        #pragma unroll
        for (int nf = 0; nf < 6; ++nf) {
            const int jcol = nf * 16 + lr;
            const bool valid = (jcol > ri) && (jcol <= ri + 31) && (mv[nf] > 0.5f);
            const float s = valid ? sacc[nf][r] * 0.015625f : -1.0e30f;
            sv[nf] = s;
            mrow = fmaxf(mrow, s);
        }
        #pragma unroll
        for (int off = 1; off <= 8; off <<= 1) mrow = fmaxf(mrow, __shfl_xor(mrow, off));
        float ls = 0.f;
        #pragma unroll
        for (int nf = 0; nf < 6; ++nf) {
            float pp = __expf(sv[nf] - mrow);
            pp = (sv[nf] > -1.0e29f) ? pp : 0.f;
            sv[nf] = pp;
            ls += pp;
        }
        #pragma unroll
        for (int off = 1; off <= 8; off <<= 1) ls += __shfl_xor(ls, off);
        const float rinv = (ls > 0.f) ? 1.f / ls : 0.f;
        #pragma unroll
        for (int nf = 0; nf < 6; ++nf)
            *(unsigned short*)(sm + ri * 208 + (nf * 16 + lr) * 2) = f2bf(sv[nf] * rinv);
    }

    // ---- Phase D: O = P V (1-term), intra-wave P dependency only.
    f32x4 oacc[4] = {};
    #pragma unroll
    for (int ks = 0; ks < 3; ++ks) {
        const bf16x8 pah = *(const bf16x8*)(sm + (w * 16 + lr) * 208 + ks * 64 + lg * 16);
        #pragma unroll
        for (int nf2 = 0; nf2 < 4; ++nf2) {
            const int dd = nf2 * 16 + lr;
            const int fold = ((dd >> 3) ^ dd) & 7;
            const bf16x8 vb = *(const bf16x8*)(sm + VT_OFF + dd * 256 + (((4 * ks + lg) ^ fold) << 4));
            oacc[nf2] = __builtin_amdgcn_mfma_f32_16x16x32_bf16(pah, vb, oacc[nf2], 0, 0, 0);
        }
    }

    // ---- Epilogue: AO bf16.
    #pragma unroll
    for (int nf2 = 0; nf2 < 4; ++nf2) {
        #pragma unroll
        for (int r = 0; r < 4; ++r) {
            const int ri = w * 16 + lg * 4 + r;
            aoh[((size_t)(n * W_SEQ + i0 + ri)) * ATTND + h * 64 + nf2 * 16 + lr] = f2bf(oacc[nf2][r]);
        }
    }
}

extern "C" void kernel_launch(void* const* d_in, const int* in_sizes, int n_in,
                              void* d_out, int out_size, void* d_ws, size_t ws_size,
                              hipStream_t stream)
{
    const float* input = (const float*)d_in[0];
    const float* mask  = (const float*)d_in[1];
    const float* W_in  = (const float*)d_in[2];
    const float* b_in  = (const float*)d_in[3];
    const float* W_fc  = (const float*)d_in[4];
    const float* b_fc  = (const float*)d_in[5];
    float* out = (float*)d_out;
    char* ws = (char*)d_ws;

    // Disjoint workspace layout (44.0 MB total, < proven-safe 62.4 MB):
    //   QKVh [0,        25165824)  bf16[8192][1536]
    //   AOh  [25165824, 33554432)  bf16[8192][512]
    //   Winh [33554432, 35127296)  bf16[1536][512]
    //   Wfch [35127296, 35651584)  bf16[512][512]
    //   Xh   [35651584, 44040192)  bf16[8192][512]
    unsigned short* QKVh = (unsigned short*)ws;
    unsigned short* AOh  = (unsigned short*)(ws + 25165824);
    unsigned short* Winh = (unsigned short*)(ws + 33554432);
    unsigned short* Wfch = (unsigned short*)(ws + 35127296);
    unsigned short* Xh   = (unsigned short*)(ws + 35651584);

    prep_x_k<<<dim3(W_SEQ / 64, C_IN / 64, N_BATCH), 256, 0, stream>>>(input, Xh);
    prep_w_k<<<(QKV_CH * C_IN / 4 + OUT_CH * ATTND / 4 + 255) / 256, 256, 0, stream>>>(
        W_in, Winh, QKV_CH * C_IN / 4, W_fc, Wfch, OUT_CH * ATTND / 4);
    gemm_bf16<0><<<dim3(QKV_CH / 128, 8192 / 128), 256, 0, stream>>>(
        Xh, Winh, b_in, QKVh, QKV_CH);
    attn4_k<<<dim3(W_SEQ / 64, NHEAD, N_BATCH), 256, 0, stream>>>(QKVh, mask, AOh);
    gemm_bf16<1><<<dim3(8192 / 128, OUT_CH / 128), 256, 0, stream>>>(
        Wfch, AOh, b_fc, out, 0);
}

// Round 7
// 52.290 us; speedup vs baseline: 9.7511x; 1.0989x over previous
//
#include <hip/hip_runtime.h>
#include <hip/hip_bf16.h>
#include <math.h>

#define W_SEQ   2048
#define C_IN    512
#define N_BATCH 4
#define NHEAD   8
#define QKV_CH  1536
#define OUT_CH  512
#define ATTND   512

typedef __attribute__((ext_vector_type(8))) short bf16x8;
typedef __attribute__((ext_vector_type(8))) unsigned short u16x8;
typedef __attribute__((ext_vector_type(4))) float f32x4;

__device__ __forceinline__ void gld16(const void* g, void* l) {
    __builtin_amdgcn_global_load_lds((const __attribute__((address_space(1))) void*)g,
                                     (__attribute__((address_space(3))) void*)l, 16, 0, 0);
}
__device__ __forceinline__ unsigned short f2bf(float f) {
    unsigned u = __float_as_uint(f);
    return (unsigned short)((u + 0x7FFFu + ((u >> 16) & 1u)) >> 16);
}

// ---------------------------------------------------------------------------
// prep_xw: blocks [0,1024): input (n,c,1,w) f32 -> Xh[m][c] bf16 via LDS
//          transpose, short8 (16B) stores.
//          blocks [1024,2048): W_in / W_fc f32 -> bf16, float4-vectorized.
// ---------------------------------------------------------------------------
__global__ __launch_bounds__(256) void prep_xw_k(const float* __restrict__ in,
                                                 unsigned short* __restrict__ xh,
                                                 const float* __restrict__ w1,
                                                 unsigned short* __restrict__ w1h, int n1_4,
                                                 const float* __restrict__ w2,
                                                 unsigned short* __restrict__ w2h, int n2_4)
{
    const int b = blockIdx.x;
    if (b < 1024) {
        __shared__ float ts[64][65];
        const int n  = b >> 8;               // 4 batches
        const int rm = b & 255;
        const int i0 = (rm & 31) * 64;       // 32 i-tiles
        const int c0 = (rm >> 5) * 64;       // 8 c-tiles
        const int t  = threadIdx.x;
        const int tx = t & 63, ty = t >> 6;
        #pragma unroll
        for (int s = 0; s < 16; ++s) {
            const int c = s * 4 + ty;
            ts[c][tx] = in[((size_t)(n * C_IN + c0 + c)) * W_SEQ + i0 + tx];
        }
        __syncthreads();
        const int c8 = t & 7, il = t >> 3;   // il in [0,32)
        #pragma unroll
        for (int s = 0; s < 2; ++s) {
            const int i = il + 32 * s;
            u16x8 hv;
            #pragma unroll
            for (int e = 0; e < 8; ++e) hv[e] = f2bf(ts[c8 * 8 + e][i]);
            *(u16x8*)(&xh[((size_t)(n * W_SEQ + i0 + i)) * C_IN + c0 + c8 * 8]) = hv;
        }
    } else {
        const int idx = (b - 1024) * 256 + threadIdx.x;
        if (idx < n1_4) {
            const float4 v = ((const float4*)w1)[idx];
            ushort4 h; h.x = f2bf(v.x); h.y = f2bf(v.y); h.z = f2bf(v.z); h.w = f2bf(v.w);
            ((ushort4*)w1h)[idx] = h;
        } else if (idx < n1_4 + n2_4) {
            const int j = idx - n1_4;
            const float4 v = ((const float4*)w2)[j];
            ushort4 h; h.x = f2bf(v.x); h.y = f2bf(v.y); h.z = f2bf(v.z); h.w = f2bf(v.w);
            ((ushort4*)w2h)[j] = h;
        }
    }
}

// ---------------------------------------------------------------------------
// 1-term bf16 MFMA GEMM: C = A * B^T (+bias), K = 512 fixed. 32 KB LDS.
// EPI 0 (GEMM1): 1-D grid of 768 blocks, XCD-grouped remap so all 12 n-tiles
//   of an m-panel land on one XCD's L2 (d%8 = XCD, A-panel reuse 12x).
//   bf16 store C[row*ldc + col] = acc + bias[col].
// EPI 1 (GEMM2): 2-D grid; f32 store
//   out[((col>>11)*512 + row)*2048 + (col&2047)] = acc + bias[row].
// ---------------------------------------------------------------------------
template<int EPI>
__global__ __launch_bounds__(256, 4) void gemm_bf16(
    const unsigned short* __restrict__ A, const unsigned short* __restrict__ B,
    const float* __restrict__ bias, void* __restrict__ Cv, const int ldc)
{
    __shared__ __align__(16) char sm[32768];
    const int t = threadIdx.x;
    const int l = t & 63, w = t >> 6;
    int bx, by;
    if (EPI == 0) {
        const int d = blockIdx.x;          // 768 = 12 x 64
        const int y8 = d & 7, r = d >> 3;  // r in [0,96)
        bx = r % 12;
        by = (r / 12) * 8 + y8;
    } else {
        bx = blockIdx.x; by = blockIdx.y;
    }
    const int m0 = by * 128, n0 = bx * 128;
    const int wm = w >> 1, wn = w & 1;

    const int subrow = l >> 3;
    const int swz    = ((l & 7) ^ subrow) << 4;
    const char* pA = (const char*)A + (size_t)m0 * 1024 + swz;
    const char* pB = (const char*)B + (size_t)n0 * 1024 + swz;

    const int frow = l & 15;
    f32x4 acc[4][4] = {};

    for (int k0 = 0; k0 < 512; k0 += 64) {
        const int kb = k0 * 2;
        #pragma unroll
        for (int c = 0; c < 4; ++c) {
            const int q = 4 * w + c;
            const size_t roff = (size_t)(q * 8 + subrow) * 1024 + kb;
            gld16(pA + roff, sm +         q * 1024);
            gld16(pB + roff, sm + 16384 + q * 1024);
        }
        __syncthreads();
        #pragma unroll
        for (int kk = 0; kk < 2; ++kk) {
            const int cswz = (kk * 64 + ((l >> 4) << 4)) ^ ((l & 7) << 4);
            bf16x8 a[4], b[4];
            #pragma unroll
            for (int mi = 0; mi < 4; ++mi)
                a[mi] = *(const bf16x8*)(sm + (wm * 64 + mi * 16 + frow) * 128 + cswz);
            #pragma unroll
            for (int ni = 0; ni < 4; ++ni)
                b[ni] = *(const bf16x8*)(sm + 16384 + (wn * 64 + ni * 16 + frow) * 128 + cswz);
            #pragma unroll
            for (int mi = 0; mi < 4; ++mi)
                #pragma unroll
                for (int ni = 0; ni < 4; ++ni)
                    acc[mi][ni] = __builtin_amdgcn_mfma_f32_16x16x32_bf16(a[mi], b[ni], acc[mi][ni], 0, 0, 0);
        }
        __syncthreads();
    }

    const int g = l >> 4;
    #pragma unroll
    for (int mi = 0; mi < 4; ++mi) {
        #pragma unroll
        for (int ni = 0; ni < 4; ++ni) {
            const int colg = n0 + wn * 64 + ni * 16 + frow;
            #pragma unroll
            for (int r = 0; r < 4; ++r) {
                const int rowg = m0 + wm * 64 + mi * 16 + g * 4 + r;
                const float v = acc[mi][ni][r];
                if (EPI == 0) {
                    ((unsigned short*)Cv)[(size_t)rowg * ldc + colg] = f2bf(v + bias[colg]);
                } else {
                    const int nb = colg >> 11, ii = colg & (W_SEQ - 1);
                    ((float*)Cv)[((size_t)(nb * OUT_CH + rowg)) * W_SEQ + ii] = v + bias[rowg];
                }
            }
        }
    }
}

// ---------------------------------------------------------------------------
// Banded MFMA attention, all-bf16 (unchanged from round 5).
// ---------------------------------------------------------------------------
#define VT_OFF  13824
#define MSK_OFF 30208
#define SM_SZ   30592

__global__ __launch_bounds__(256, 4) void attn4_k(const unsigned short* __restrict__ qkv,
                                                  const float* __restrict__ mask,
                                                  unsigned short* __restrict__ aoh)
{
    __shared__ __align__(16) char sm[SM_SZ];
    const int t = threadIdx.x, l = t & 63, w = t >> 6;
    const int i0 = blockIdx.x * 64, h = blockIdx.y, n = blockIdx.z;
    const int lr = l & 15, lg = l >> 4;

    const char* tb = (const char*)qkv + ((size_t)n * W_SEQ * QKV_CH + h * 192) * 2;

    const int r8 = l >> 3, c8 = l & 7;
    #pragma unroll
    for (int it = 0; it < 3; ++it) {
        const int jl = w * 24 + it * 8 + r8;
        const int jg = i0 - 16 + jl;
        bf16x8 kv = {}, vv = {};
        if (jg >= 0 && jg < W_SEQ) {
            const char* rp = tb + (size_t)jg * 3072;
            kv = *(const bf16x8*)(rp + 128 + c8 * 16);
            vv = *(const bf16x8*)(rp + 256 + c8 * 16);
        }
        *(bf16x8*)(sm + jl * 144 + c8 * 16) = kv;
        const int J0 = jl >> 3;
        #pragma unroll
        for (int e = 0; e < 8; ++e) {
            const int d = c8 * 8 + e;
            const int fold = ((d >> 3) ^ d) & 7;
            *(unsigned short*)(sm + VT_OFF + d * 256 + (((J0 ^ fold) << 4) | ((jl & 7) * 2)))
                = (unsigned short)vv[e];
        }
    }
    bf16x8 qh[2];
    {
        const char* qrow = tb + (size_t)(i0 + w * 16 + lr) * 3072 + lg * 16;
        qh[0] = *(const bf16x8*)(qrow);
        qh[1] = *(const bf16x8*)(qrow + 64);
    }
    if (t < 96) {
        const int jg = i0 - 16 + t;
        *(float*)(sm + MSK_OFF + t * 4) = (jg >= 0 && jg < W_SEQ) ? mask[n * W_SEQ + jg] : 0.f;
    }
    __syncthreads();

    f32x4 sacc[6] = {};
    #pragma unroll
    for (int nf = 0; nf < 6; ++nf) {
        #pragma unroll
        for (int kk = 0; kk < 2; ++kk) {
            const bf16x8 kh = *(const bf16x8*)(sm + (nf * 16 + lr) * 144 + kk * 64 + lg * 16);
            sacc[nf] = __builtin_amdgcn_mfma_f32_16x16x32_bf16(qh[kk], kh, sacc[nf], 0, 0, 0);
        }
    }
    __syncthreads();

    float mv[6];
    #pragma unroll
    for (int nf = 0; nf < 6; ++nf)
        mv[nf] = *(const float*)(sm + MSK_OFF + (nf * 16 + lr) * 4);

    #pragma unroll
    for (int r = 0; r < 4; ++r) {
        const int ri = w * 16 + lg * 4 + r;
        float sv[6], mrow = -1.0e30f;
        #pragma unroll
        for (int nf = 0; nf < 6; ++nf) {
            const int jcol = nf * 16 + lr;
            const bool valid = (jcol > ri) && (jcol <= ri + 31) && (mv[nf] > 0.5f);
            const float s = valid ? sacc[nf][r] * 0.015625f : -1.0e30f;
            sv[nf] = s;
            mrow = fmaxf(mrow, s);
        }
        #pragma unroll
        for (int off = 1; off <= 8; off <<= 1) mrow = fmaxf(mrow, __shfl_xor(mrow, off));
        float ls = 0.f;
        #pragma unroll
        for (int nf = 0; nf < 6; ++nf) {
            float pp = __expf(sv[nf] - mrow);
            pp = (sv[nf] > -1.0e29f) ? pp : 0.f;
            sv[nf] = pp;
            ls += pp;
        }
        #pragma unroll
        for (int off = 1; off <= 8; off <<= 1) ls += __shfl_xor(ls, off);
        const float rinv = (ls > 0.f) ? 1.f / ls : 0.f;
        #pragma unroll
        for (int nf = 0; nf < 6; ++nf)
            *(unsigned short*)(sm + ri * 208 + (nf * 16 + lr) * 2) = f2bf(sv[nf] * rinv);
    }

    f32x4 oacc[4] = {};
    #pragma unroll
    for (int ks = 0; ks < 3; ++ks) {
        const bf16x8 pah = *(const bf16x8*)(sm + (w * 16 + lr) * 208 + ks * 64 + lg * 16);
        #pragma unroll
        for (int nf2 = 0; nf2 < 4; ++nf2) {
            const int dd = nf2 * 16 + lr;
            const int fold = ((dd >> 3) ^ dd) & 7;
            const bf16x8 vb = *(const bf16x8*)(sm + VT_OFF + dd * 256 + (((4 * ks + lg) ^ fold) << 4));
            oacc[nf2] = __builtin_amdgcn_mfma_f32_16x16x32_bf16(pah, vb, oacc[nf2], 0, 0, 0);
        }
    }

    #pragma unroll
    for (int nf2 = 0; nf2 < 4; ++nf2) {
        #pragma unroll
        for (int r = 0; r < 4; ++r) {
            const int ri = w * 16 + lg * 4 + r;
            aoh[((size_t)(n * W_SEQ + i0 + ri)) * ATTND + h * 64 + nf2 * 16 + lr] = f2bf(oacc[nf2][r]);
        }
    }
}

extern "C" void kernel_launch(void* const* d_in, const int* in_sizes, int n_in,
                              void* d_out, int out_size, void* d_ws, size_t ws_size,
                              hipStream_t stream)
{
    const float* input = (const float*)d_in[0];
    const float* mask  = (const float*)d_in[1];
    const float* W_in  = (const float*)d_in[2];
    const float* b_in  = (const float*)d_in[3];
    const float* W_fc  = (const float*)d_in[4];
    const float* b_fc  = (const float*)d_in[5];
    float* out = (float*)d_out;
    char* ws = (char*)d_ws;

    // Disjoint workspace layout (44.0 MB total):
    //   QKVh [0,        25165824)  bf16[8192][1536]
    //   AOh  [25165824, 33554432)  bf16[8192][512]
    //   Winh [33554432, 35127296)  bf16[1536][512]
    //   Wfch [35127296, 35651584)  bf16[512][512]
    //   Xh   [35651584, 44040192)  bf16[8192][512]
    unsigned short* QKVh = (unsigned short*)ws;
    unsigned short* AOh  = (unsigned short*)(ws + 25165824);
    unsigned short* Winh = (unsigned short*)(ws + 33554432);
    unsigned short* Wfch = (unsigned short*)(ws + 35127296);
    unsigned short* Xh   = (unsigned short*)(ws + 35651584);

    prep_xw_k<<<dim3(2048), 256, 0, stream>>>(input, Xh,
                                              W_in, Winh, QKV_CH * C_IN / 4,
                                              W_fc, Wfch, OUT_CH * ATTND / 4);
    gemm_bf16<0><<<dim3(768), 256, 0, stream>>>(Xh, Winh, b_in, QKVh, QKV_CH);
    attn4_k<<<dim3(W_SEQ / 64, NHEAD, N_BATCH), 256, 0, stream>>>(QKVh, mask, AOh);
    gemm_bf16<1><<<dim3(8192 / 128, OUT_CH / 128), 256, 0, stream>>>(
        Wfch, AOh, b_fc, out, 0);
}

// Round 10
// 50.438 us; speedup vs baseline: 10.1091x; 1.0367x over previous
//
#include <hip/hip_runtime.h>
#include <hip/hip_bf16.h>
#include <math.h>

#define W_SEQ   2048
#define C_IN    512
#define N_BATCH 4
#define NHEAD   8
#define QKV_CH  1536
#define OUT_CH  512
#define ATTND   512
#define N1_4    (QKV_CH * C_IN / 4)
#define N2_4    (OUT_CH * ATTND / 4)

typedef __attribute__((ext_vector_type(8))) short bf16x8;
typedef __attribute__((ext_vector_type(8))) unsigned short u16x8;
typedef __attribute__((ext_vector_type(4))) float f32x4;

__device__ __forceinline__ void gld16(const void* g, void* l) {
    __builtin_amdgcn_global_load_lds((const __attribute__((address_space(1))) void*)g,
                                     (__attribute__((address_space(3))) void*)l, 16, 0, 0);
}
__device__ __forceinline__ unsigned short f2bf(float f) {
    unsigned u = __float_as_uint(f);
    return (unsigned short)((u + 0x7FFFu + ((u >> 16) & 1u)) >> 16);
}

// ---------------------------------------------------------------------------
// Device-scope grid barrier: each barrier slot used once per launch; slots
// zeroed by a hipMemsetAsync node at the head of every kernel_launch call.
// ---------------------------------------------------------------------------
__device__ __forceinline__ void grid_sync(unsigned* bar, unsigned target) {
    __syncthreads();
    if (threadIdx.x == 0) {
        __threadfence();                          // release (device scope)
        atomicAdd(bar, 1u);
        while (atomicAdd(bar, 0u) < target)       // device-coherent read
            __builtin_amdgcn_s_sleep(8);
        __threadfence();                          // acquire
    }
    __syncthreads();
}

// ---------------------------------------------------------------------------
// P0 unit: X transpose-convert (unit b of 1024) + weight convert chunk b.
// ---------------------------------------------------------------------------
__device__ __forceinline__ void prep_unit(char* sm, int b,
    const float* __restrict__ input, unsigned short* __restrict__ Xh,
    const float* __restrict__ W_in, unsigned short* __restrict__ Winh,
    const float* __restrict__ W_fc, unsigned short* __restrict__ Wfch)
{
    const int t = threadIdx.x;
    float (*ts)[65] = (float(*)[65])sm;
    const int n  = b >> 8, rm = b & 255;
    const int i0 = (rm & 31) * 64, c0 = (rm >> 5) * 64;
    const int tx = t & 63, ty = t >> 6;
    #pragma unroll
    for (int s = 0; s < 16; ++s) {
        const int c = s * 4 + ty;
        ts[c][tx] = input[((size_t)(n * C_IN + c0 + c)) * W_SEQ + i0 + tx];
    }
    __syncthreads();
    const int c8 = t & 7, il = t >> 3;
    #pragma unroll
    for (int s = 0; s < 2; ++s) {
        const int i = il + 32 * s;
        u16x8 hv;
        #pragma unroll
        for (int e = 0; e < 8; ++e) hv[e] = f2bf(ts[c8 * 8 + e][i]);
        *(u16x8*)(&Xh[((size_t)(n * W_SEQ + i0 + i)) * C_IN + c0 + c8 * 8]) = hv;
    }
    const int idx = b * 256 + t;               // [0, 262144) == N1_4 + N2_4
    if (idx < N1_4) {
        const float4 v = ((const float4*)W_in)[idx];
        ushort4 hh; hh.x = f2bf(v.x); hh.y = f2bf(v.y); hh.z = f2bf(v.z); hh.w = f2bf(v.w);
        ((ushort4*)Winh)[idx] = hh;
    } else {
        const int j = idx - N1_4;
        const float4 v = ((const float4*)W_fc)[j];
        ushort4 hh; hh.x = f2bf(v.x); hh.y = f2bf(v.y); hh.z = f2bf(v.z); hh.w = f2bf(v.w);
        ((ushort4*)Wfch)[j] = hh;
    }
}

// ---------------------------------------------------------------------------
// GEMM body: C = A * B^T (+bias), K = 512, 128x128 tile, 32 KB LDS arena.
// EPI 0: bf16 store C[row*ldc+col] = acc + bias[col]
// EPI 1: f32 store out[((col>>11)*512+row)*2048 + (col&2047)] = acc + bias[row]
// ---------------------------------------------------------------------------
template<int EPI>
__device__ __forceinline__ void gemm_body(char* sm, int bx, int by,
    const unsigned short* __restrict__ A, const unsigned short* __restrict__ B,
    const float* __restrict__ bias, void* __restrict__ Cv, const int ldc)
{
    const int t = threadIdx.x;
    const int l = t & 63, w = t >> 6;
    const int m0 = by * 128, n0 = bx * 128;
    const int wm = w >> 1, wn = w & 1;

    const int subrow = l >> 3;
    const int swz    = ((l & 7) ^ subrow) << 4;
    const char* pA = (const char*)A + (size_t)m0 * 1024 + swz;
    const char* pB = (const char*)B + (size_t)n0 * 1024 + swz;

    const int frow = l & 15;
    f32x4 acc[4][4] = {};

    for (int k0 = 0; k0 < 512; k0 += 64) {
        const int kb = k0 * 2;
        #pragma unroll
        for (int c = 0; c < 4; ++c) {
            const int q = 4 * w + c;
            const size_t roff = (size_t)(q * 8 + subrow) * 1024 + kb;
            gld16(pA + roff, sm +         q * 1024);
            gld16(pB + roff, sm + 16384 + q * 1024);
        }
        __syncthreads();
        #pragma unroll
        for (int kk = 0; kk < 2; ++kk) {
            const int cswz = (kk * 64 + ((l >> 4) << 4)) ^ ((l & 7) << 4);
            bf16x8 a[4], b[4];
            #pragma unroll
            for (int mi = 0; mi < 4; ++mi)
                a[mi] = *(const bf16x8*)(sm + (wm * 64 + mi * 16 + frow) * 128 + cswz);
            #pragma unroll
            for (int ni = 0; ni < 4; ++ni)
                b[ni] = *(const bf16x8*)(sm + 16384 + (wn * 64 + ni * 16 + frow) * 128 + cswz);
            #pragma unroll
            for (int mi = 0; mi < 4; ++mi)
                #pragma unroll
                for (int ni = 0; ni < 4; ++ni)
                    acc[mi][ni] = __builtin_amdgcn_mfma_f32_16x16x32_bf16(a[mi], b[ni], acc[mi][ni], 0, 0, 0);
        }
        __syncthreads();
    }

    const int g = l >> 4;
    #pragma unroll
    for (int mi = 0; mi < 4; ++mi) {
        #pragma unroll
        for (int ni = 0; ni < 4; ++ni) {
            const int colg = n0 + wn * 64 + ni * 16 + frow;
            #pragma unroll
            for (int r = 0; r < 4; ++r) {
                const int rowg = m0 + wm * 64 + mi * 16 + g * 4 + r;
                const float v = acc[mi][ni][r];
                if (EPI == 0) {
                    ((unsigned short*)Cv)[(size_t)rowg * ldc + colg] = f2bf(v + bias[colg]);
                } else {
                    const int nb = colg >> 11, ii = colg & (W_SEQ - 1);
                    ((float*)Cv)[((size_t)(nb * OUT_CH + rowg)) * W_SEQ + ii] = v + bias[rowg];
                }
            }
        }
    }
}

// ---------------------------------------------------------------------------
// Banded MFMA attention body (proven attn4 math). LDS: K[96][144B] @0
// (P[64][208B] overlays), VT[64][256B] @13824 (chunk-XOR swizzle),
// mask f32[96] @30208. 30592 B within the 32 KB arena.
// ---------------------------------------------------------------------------
#define VT_OFF  13824
#define MSK_OFF 30208

__device__ __forceinline__ void attn_body(char* sm, int blk,
    const unsigned short* __restrict__ qkv, const float* __restrict__ mask,
    unsigned short* __restrict__ aoh)
{
    const int t = threadIdx.x, l = t & 63, w = t >> 6;
    const int i0 = (blk & 31) * 64, h = (blk >> 5) & 7, n = blk >> 8;
    const int lr = l & 15, lg = l >> 4;

    const char* tb = (const char*)qkv + ((size_t)n * W_SEQ * QKV_CH + h * 192) * 2;

    const int r8 = l >> 3, c8 = l & 7;
    #pragma unroll
    for (int it = 0; it < 3; ++it) {
        const int jl = w * 24 + it * 8 + r8;
        const int jg = i0 - 16 + jl;
        bf16x8 kv = {}, vv = {};
        if (jg >= 0 && jg < W_SEQ) {
            const char* rp = tb + (size_t)jg * 3072;
            kv = *(const bf16x8*)(rp + 128 + c8 * 16);
            vv = *(const bf16x8*)(rp + 256 + c8 * 16);
        }
        *(bf16x8*)(sm + jl * 144 + c8 * 16) = kv;
        const int J0 = jl >> 3;
        #pragma unroll
        for (int e = 0; e < 8; ++e) {
            const int d = c8 * 8 + e;
            const int fold = ((d >> 3) ^ d) & 7;
            *(unsigned short*)(sm + VT_OFF + d * 256 + (((J0 ^ fold) << 4) | ((jl & 7) * 2)))
                = (unsigned short)vv[e];
        }
    }
    bf16x8 qh[2];
    {
        const char* qrow = tb + (size_t)(i0 + w * 16 + lr) * 3072 + lg * 16;
        qh[0] = *(const bf16x8*)(qrow);
        qh[1] = *(const bf16x8*)(qrow + 64);
    }
    if (t < 96) {
        const int jg = i0 - 16 + t;
        *(float*)(sm + MSK_OFF + t * 4) = (jg >= 0 && jg < W_SEQ) ? mask[n * W_SEQ + jg] : 0.f;
    }
    __syncthreads();

    f32x4 sacc[6] = {};
    #pragma unroll
    for (int nf = 0; nf < 6; ++nf) {
        #pragma unroll
        for (int kk = 0; kk < 2; ++kk) {
            const bf16x8 kh = *(const bf16x8*)(sm + (nf * 16 + lr) * 144 + kk * 64 + lg * 16);
            sacc[nf] = __builtin_amdgcn_mfma_f32_16x16x32_bf16(qh[kk], kh, sacc[nf], 0, 0, 0);
        }
    }
    __syncthreads();

    float mv[6];
    #pragma unroll
    for (int nf = 0; nf < 6; ++nf)
        mv[nf] = *(const float*)(sm + MSK_OFF + (nf * 16 + lr) * 4);

    #pragma unroll
    for (int r = 0; r < 4; ++r) {
        const int ri = w * 16 + lg * 4 + r;
        float sv[6], mrow = -1.0e30f;
        #pragma unroll
        for (int nf = 0; nf < 6; ++nf) {
            const int jcol = nf * 16 + lr;
            const bool valid = (jcol > ri) && (jcol <= ri + 31) && (mv[nf] > 0.5f);
            const float s = valid ? sacc[nf][r] * 0.015625f : -1.0e30f;
            sv[nf] = s;
            mrow = fmaxf(mrow, s);
        }
        #pragma unroll
        for (int off = 1; off <= 8; off <<= 1) mrow = fmaxf(mrow, __shfl_xor(mrow, off));
        float ls = 0.f;
        #pragma unroll
        for (int nf = 0; nf < 6; ++nf) {
            float pp = __expf(sv[nf] - mrow);
            pp = (sv[nf] > -1.0e29f) ? pp : 0.f;
            sv[nf] = pp;
            ls += pp;
        }
        #pragma unroll
        for (int off = 1; off <= 8; off <<= 1) ls += __shfl_xor(ls, off);
        const float rinv = (ls > 0.f) ? 1.f / ls : 0.f;
        #pragma unroll
        for (int nf = 0; nf < 6; ++nf)
            *(unsigned short*)(sm + ri * 208 + (nf * 16 + lr) * 2) = f2bf(sv[nf] * rinv);
    }

    f32x4 oacc[4] = {};
    #pragma unroll
    for (int ks = 0; ks < 3; ++ks) {
        const bf16x8 pah = *(const bf16x8*)(sm + (w * 16 + lr) * 208 + ks * 64 + lg * 16);
        #pragma unroll
        for (int nf2 = 0; nf2 < 4; ++nf2) {
            const int dd = nf2 * 16 + lr;
            const int fold = ((dd >> 3) ^ dd) & 7;
            const bf16x8 vb = *(const bf16x8*)(sm + VT_OFF + dd * 256 + (((4 * ks + lg) ^ fold) << 4));
            oacc[nf2] = __builtin_amdgcn_mfma_f32_16x16x32_bf16(pah, vb, oacc[nf2], 0, 0, 0);
        }
    }

    #pragma unroll
    for (int nf2 = 0; nf2 < 4; ++nf2) {
        #pragma unroll
        for (int r = 0; r < 4; ++r) {
            const int ri = w * 16 + lg * 4 + r;
            aoh[((size_t)(n * W_SEQ + i0 + ri)) * ATTND + h * 64 + nf2 * 16 + lr] = f2bf(oacc[nf2][r]);
        }
    }
}

// ---------------------------------------------------------------------------
// Fused persistent kernel, plain launch + manual grid barriers.
// Grid MUST be fully co-resident: G = 1024 @ 4 blk/CU (host-verified).
// ---------------------------------------------------------------------------
__global__ __launch_bounds__(256, 4) void fused_all_k(
    const float* __restrict__ input, const float* __restrict__ mask,
    const float* __restrict__ W_in,  const float* __restrict__ b_in,
    const float* __restrict__ W_fc,  const float* __restrict__ b_fc,
    float* __restrict__ out,
    unsigned short* __restrict__ QKVh, unsigned short* __restrict__ AOh,
    unsigned short* __restrict__ Winh, unsigned short* __restrict__ Wfch,
    unsigned short* __restrict__ Xh, unsigned* __restrict__ bar)
{
    __shared__ __align__(16) char sm[32768];
    const int G = gridDim.x;

    for (int u = blockIdx.x; u < 1024; u += G) {
        prep_unit(sm, u, input, Xh, W_in, Winh, W_fc, Wfch);
        __syncthreads();
    }
    grid_sync(bar + 0, G);

    for (int u = blockIdx.x; u < 768; u += G) {
        const int y8 = u & 7, r = u >> 3;
        gemm_body<0>(sm, r % 12, (r / 12) * 8 + y8, Xh, Winh, b_in, QKVh, QKV_CH);
        __syncthreads();
    }
    grid_sync(bar + 16, G);

    for (int u = blockIdx.x; u < 1024; u += G) {
        attn_body(sm, u, QKVh, mask, AOh);
        __syncthreads();
    }
    grid_sync(bar + 32, G);

    for (int u = blockIdx.x; u < 256; u += G)
        gemm_body<1>(sm, u >> 2, u & 3, Wfch, AOh, b_fc, out, 0);
}

// ---------------------------------------------------------------------------
// Fallback separate kernels (proven round-7 path) over the same bodies.
// ---------------------------------------------------------------------------
__global__ __launch_bounds__(256, 4) void prep_sep_k(
    const float* __restrict__ input, unsigned short* __restrict__ Xh,
    const float* __restrict__ W_in, unsigned short* __restrict__ Winh,
    const float* __restrict__ W_fc, unsigned short* __restrict__ Wfch)
{
    __shared__ __align__(16) char sm[32768];
    prep_unit(sm, blockIdx.x, input, Xh, W_in, Winh, W_fc, Wfch);
}
__global__ __launch_bounds__(256, 4) void gemm1_sep_k(
    const unsigned short* __restrict__ A, const unsigned short* __restrict__ B,
    const float* __restrict__ bias, unsigned short* __restrict__ C)
{
    __shared__ __align__(16) char sm[32768];
    const int d = blockIdx.x, y8 = d & 7, r = d >> 3;
    gemm_body<0>(sm, r % 12, (r / 12) * 8 + y8, A, B, bias, C, QKV_CH);
}
__global__ __launch_bounds__(256, 4) void attn_sep_k(
    const unsigned short* __restrict__ qkv, const float* __restrict__ mask,
    unsigned short* __restrict__ aoh)
{
    __shared__ __align__(16) char sm[32768];
    attn_body(sm, blockIdx.x, qkv, mask, aoh);
}
__global__ __launch_bounds__(256, 4) void gemm2_sep_k(
    const unsigned short* __restrict__ A, const unsigned short* __restrict__ B,
    const float* __restrict__ bias, float* __restrict__ out)
{
    __shared__ __align__(16) char sm[32768];
    gemm_body<1>(sm, blockIdx.x >> 2, blockIdx.x & 3, A, B, bias, out, 0);
}

extern "C" void kernel_launch(void* const* d_in, const int* in_sizes, int n_in,
                              void* d_out, int out_size, void* d_ws, size_t ws_size,
                              hipStream_t stream)
{
    const float* input = (const float*)d_in[0];
    const float* mask  = (const float*)d_in[1];
    const float* W_in  = (const float*)d_in[2];
    const float* b_in  = (const float*)d_in[3];
    const float* W_fc  = (const float*)d_in[4];
    const float* b_fc  = (const float*)d_in[5];
    float* out = (float*)d_out;
    char* ws = (char*)d_ws;

    // Workspace layout:
    //   QKVh [0,        25165824)  bf16[8192][1536]
    //   AOh  [25165824, 33554432)  bf16[8192][512]
    //   Winh [33554432, 35127296)  bf16[1536][512]
    //   Wfch [35127296, 35651584)  bf16[512][512]
    //   Xh   [35651584, 44040192)  bf16[8192][512]
    //   bar  [46137344, 46137472)  3 x unsigned barrier slots (64B apart)
    unsigned short* QKVh = (unsigned short*)ws;
    unsigned short* AOh  = (unsigned short*)(ws + 25165824);
    unsigned short* Winh = (unsigned short*)(ws + 33554432);
    unsigned short* Wfch = (unsigned short*)(ws + 35127296);
    unsigned short* Xh   = (unsigned short*)(ws + 35651584);
    unsigned*       bar  = (unsigned*)(ws + 46137344);

    // Host-side occupancy check (pure queries, deterministic, capture-safe).
    int occ = 0;
    hipOccupancyMaxActiveBlocksPerMultiprocessor(&occ, fused_all_k, 256, 0);

    if (occ >= 4) {
        hipMemsetAsync(bar, 0, 192, stream);   // zero barrier slots (graph node)
        fused_all_k<<<dim3(1024), 256, 0, stream>>>(
            input, mask, W_in, b_in, W_fc, b_fc, out,
            QKVh, AOh, Winh, Wfch, Xh, bar);
    } else {
        prep_sep_k <<<dim3(1024), 256, 0, stream>>>(input, Xh, W_in, Winh, W_fc, Wfch);
        gemm1_sep_k<<<dim3(768),  256, 0, stream>>>(Xh, Winh, b_in, QKVh);
        attn_sep_k <<<dim3(1024), 256, 0, stream>>>(QKVh, mask, AOh);
        gemm2_sep_k<<<dim3(256),  256, 0, stream>>>(Wfch, AOh, b_fc, out);
    }
}

// Round 11
// 50.393 us; speedup vs baseline: 10.1182x; 1.0009x over previous
//
#include <hip/hip_runtime.h>
#include <hip/hip_bf16.h>
#include <math.h>

#define W_SEQ   2048
#define C_IN    512
#define N_BATCH 4
#define NHEAD   8
#define QKV_CH  1536
#define OUT_CH  512
#define ATTND   512
#define N1_4    (QKV_CH * C_IN / 4)
#define N2_4    (OUT_CH * ATTND / 4)

typedef __attribute__((ext_vector_type(8))) short bf16x8;
typedef __attribute__((ext_vector_type(8))) unsigned short u16x8;
typedef __attribute__((ext_vector_type(4))) float f32x4;

__device__ __forceinline__ void gld16(const void* g, void* l) {
    __builtin_amdgcn_global_load_lds((const __attribute__((address_space(1))) void*)g,
                                     (__attribute__((address_space(3))) void*)l, 16, 0, 0);
}
__device__ __forceinline__ unsigned short f2bf(float f) {
    unsigned u = __float_as_uint(f);
    return (unsigned short)((u + 0x7FFFu + ((u >> 16) & 1u)) >> 16);
}
__device__ __forceinline__ unsigned ld_flag(const unsigned* p) {
    return __hip_atomic_load(p, __ATOMIC_RELAXED, __HIP_MEMORY_SCOPE_AGENT);
}

// ---------------------------------------------------------------------------
// Flag region layout (all counters 64 B apart to avoid same-line atomics):
//   leaf[64]   @ 0      (tree barrier leaves, 16 arrivals each)
//   root       @ 4096   (64 arrivals)  ; release @ 4160
//   qdone[64]  @ 8192   (12 arrivals per QKV 128-row m-panel)
//   adone[64]  @ 12288  (16 arrivals per AO 128-row m-panel)
// Zeroed by hipMemsetAsync each launch.
// ---------------------------------------------------------------------------
__device__ __forceinline__ void tree_barrier(unsigned* flg) {
    __syncthreads();
    if (threadIdx.x == 0) {
        __threadfence();
        unsigned* leaf = flg + (blockIdx.x >> 4) * 16;
        unsigned* root = flg + 1024;
        unsigned* rel  = flg + 1040;
        if (atomicAdd(leaf, 1u) == 15u)
            if (atomicAdd(root, 1u) == 63u)
                __hip_atomic_store(rel, 1u, __ATOMIC_RELEASE, __HIP_MEMORY_SCOPE_AGENT);
        while (ld_flag(rel) == 0u) __builtin_amdgcn_s_sleep(2);
        __threadfence();
    }
    __syncthreads();
}

// ---------------------------------------------------------------------------
// P0 unit: X transpose-convert (unit b of 1024) + weight convert chunk b.
// ---------------------------------------------------------------------------
__device__ __forceinline__ void prep_unit(char* sm, int b,
    const float* __restrict__ input, unsigned short* __restrict__ Xh,
    const float* __restrict__ W_in, unsigned short* __restrict__ Winh,
    const float* __restrict__ W_fc, unsigned short* __restrict__ Wfch)
{
    const int t = threadIdx.x;
    float (*ts)[65] = (float(*)[65])sm;
    const int n  = b >> 8, rm = b & 255;
    const int i0 = (rm & 31) * 64, c0 = (rm >> 5) * 64;
    const int tx = t & 63, ty = t >> 6;
    #pragma unroll
    for (int s = 0; s < 16; ++s) {
        const int c = s * 4 + ty;
        ts[c][tx] = input[((size_t)(n * C_IN + c0 + c)) * W_SEQ + i0 + tx];
    }
    __syncthreads();
    const int c8 = t & 7, il = t >> 3;
    #pragma unroll
    for (int s = 0; s < 2; ++s) {
        const int i = il + 32 * s;
        u16x8 hv;
        #pragma unroll
        for (int e = 0; e < 8; ++e) hv[e] = f2bf(ts[c8 * 8 + e][i]);
        *(u16x8*)(&Xh[((size_t)(n * W_SEQ + i0 + i)) * C_IN + c0 + c8 * 8]) = hv;
    }
    const int idx = b * 256 + t;               // [0, 262144) == N1_4 + N2_4
    if (idx < N1_4) {
        const float4 v = ((const float4*)W_in)[idx];
        ushort4 hh; hh.x = f2bf(v.x); hh.y = f2bf(v.y); hh.z = f2bf(v.z); hh.w = f2bf(v.w);
        ((ushort4*)Winh)[idx] = hh;
    } else {
        const int j = idx - N1_4;
        const float4 v = ((const float4*)W_fc)[j];
        ushort4 hh; hh.x = f2bf(v.x); hh.y = f2bf(v.y); hh.z = f2bf(v.z); hh.w = f2bf(v.w);
        ((ushort4*)Wfch)[j] = hh;
    }
}

// ---------------------------------------------------------------------------
// GEMM body: C = A * B^T (+bias), K = 512, 128x128 tile, 32 KB LDS arena.
// EPI 0: bf16 store C[row*ldc+col] = acc + bias[col]
// EPI 1: f32 store out[((col>>11)*512+row)*2048 + (col&2047)] = acc + bias[row]
// ---------------------------------------------------------------------------
template<int EPI>
__device__ __forceinline__ void gemm_body(char* sm, int bx, int by,
    const unsigned short* __restrict__ A, const unsigned short* __restrict__ B,
    const float* __restrict__ bias, void* __restrict__ Cv, const int ldc)
{
    const int t = threadIdx.x;
    const int l = t & 63, w = t >> 6;
    const int m0 = by * 128, n0 = bx * 128;
    const int wm = w >> 1, wn = w & 1;

    const int subrow = l >> 3;
    const int swz    = ((l & 7) ^ subrow) << 4;
    const char* pA = (const char*)A + (size_t)m0 * 1024 + swz;
    const char* pB = (const char*)B + (size_t)n0 * 1024 + swz;

    const int frow = l & 15;
    f32x4 acc[4][4] = {};

    for (int k0 = 0; k0 < 512; k0 += 64) {
        const int kb = k0 * 2;
        #pragma unroll
        for (int c = 0; c < 4; ++c) {
            const int q = 4 * w + c;
            const size_t roff = (size_t)(q * 8 + subrow) * 1024 + kb;
            gld16(pA + roff, sm +         q * 1024);
            gld16(pB + roff, sm + 16384 + q * 1024);
        }
        __syncthreads();
        #pragma unroll
        for (int kk = 0; kk < 2; ++kk) {
            const int cswz = (kk * 64 + ((l >> 4) << 4)) ^ ((l & 7) << 4);
            bf16x8 a[4], b[4];
            #pragma unroll
            for (int mi = 0; mi < 4; ++mi)
                a[mi] = *(const bf16x8*)(sm + (wm * 64 + mi * 16 + frow) * 128 + cswz);
            #pragma unroll
            for (int ni = 0; ni < 4; ++ni)
                b[ni] = *(const bf16x8*)(sm + 16384 + (wn * 64 + ni * 16 + frow) * 128 + cswz);
            #pragma unroll
            for (int mi = 0; mi < 4; ++mi)
                #pragma unroll
                for (int ni = 0; ni < 4; ++ni)
                    acc[mi][ni] = __builtin_amdgcn_mfma_f32_16x16x32_bf16(a[mi], b[ni], acc[mi][ni], 0, 0, 0);
        }
        __syncthreads();
    }

    const int g = l >> 4;
    #pragma unroll
    for (int mi = 0; mi < 4; ++mi) {
        #pragma unroll
        for (int ni = 0; ni < 4; ++ni) {
            const int colg = n0 + wn * 64 + ni * 16 + frow;
            #pragma unroll
            for (int r = 0; r < 4; ++r) {
                const int rowg = m0 + wm * 64 + mi * 16 + g * 4 + r;
                const float v = acc[mi][ni][r];
                if (EPI == 0) {
                    ((unsigned short*)Cv)[(size_t)rowg * ldc + colg] = f2bf(v + bias[colg]);
                } else {
                    const int nb = colg >> 11, ii = colg & (W_SEQ - 1);
                    ((float*)Cv)[((size_t)(nb * OUT_CH + rowg)) * W_SEQ + ii] = v + bias[rowg];
                }
            }
        }
    }
}

// ---------------------------------------------------------------------------
// Banded MFMA attention body (proven attn4 math). LDS: K[96][144B] @0
// (P[64][208B] overlays), VT[64][256B] @13824 (chunk-XOR swizzle),
// mask f32[96] @30208. 30592 B within the 32 KB arena.
// ---------------------------------------------------------------------------
#define VT_OFF  13824
#define MSK_OFF 30208

__device__ __forceinline__ void attn_body(char* sm, int blk,
    const unsigned short* __restrict__ qkv, const float* __restrict__ mask,
    unsigned short* __restrict__ aoh)
{
    const int t = threadIdx.x, l = t & 63, w = t >> 6;
    const int i0 = (blk & 31) * 64, h = (blk >> 5) & 7, n = blk >> 8;
    const int lr = l & 15, lg = l >> 4;

    const char* tb = (const char*)qkv + ((size_t)n * W_SEQ * QKV_CH + h * 192) * 2;

    const int r8 = l >> 3, c8 = l & 7;
    #pragma unroll
    for (int it = 0; it < 3; ++it) {
        const int jl = w * 24 + it * 8 + r8;
        const int jg = i0 - 16 + jl;
        bf16x8 kv = {}, vv = {};
        if (jg >= 0 && jg < W_SEQ) {
            const char* rp = tb + (size_t)jg * 3072;
            kv = *(const bf16x8*)(rp + 128 + c8 * 16);
            vv = *(const bf16x8*)(rp + 256 + c8 * 16);
        }
        *(bf16x8*)(sm + jl * 144 + c8 * 16) = kv;
        const int J0 = jl >> 3;
        #pragma unroll
        for (int e = 0; e < 8; ++e) {
            const int d = c8 * 8 + e;
            const int fold = ((d >> 3) ^ d) & 7;
            *(unsigned short*)(sm + VT_OFF + d * 256 + (((J0 ^ fold) << 4) | ((jl & 7) * 2)))
                = (unsigned short)vv[e];
        }
    }
    bf16x8 qh[2];
    {
        const char* qrow = tb + (size_t)(i0 + w * 16 + lr) * 3072 + lg * 16;
        qh[0] = *(const bf16x8*)(qrow);
        qh[1] = *(const bf16x8*)(qrow + 64);
    }
    if (t < 96) {
        const int jg = i0 - 16 + t;
        *(float*)(sm + MSK_OFF + t * 4) = (jg >= 0 && jg < W_SEQ) ? mask[n * W_SEQ + jg] : 0.f;
    }
    __syncthreads();

    f32x4 sacc[6] = {};
    #pragma unroll
    for (int nf = 0; nf < 6; ++nf) {
        #pragma unroll
        for (int kk = 0; kk < 2; ++kk) {
            const bf16x8 kh = *(const bf16x8*)(sm + (nf * 16 + lr) * 144 + kk * 64 + lg * 16);
            sacc[nf] = __builtin_amdgcn_mfma_f32_16x16x32_bf16(qh[kk], kh, sacc[nf], 0, 0, 0);
        }
    }
    __syncthreads();

    float mv[6];
    #pragma unroll
    for (int nf = 0; nf < 6; ++nf)
        mv[nf] = *(const float*)(sm + MSK_OFF + (nf * 16 + lr) * 4);

    #pragma unroll
    for (int r = 0; r < 4; ++r) {
        const int ri = w * 16 + lg * 4 + r;
        float sv[6], mrow = -1.0e30f;
        #pragma unroll
        for (int nf = 0; nf < 6; ++nf) {
            const int jcol = nf * 16 + lr;
            const bool valid = (jcol > ri) && (jcol <= ri + 31) && (mv[nf] > 0.5f);
            const float s = valid ? sacc[nf][r] * 0.015625f : -1.0e30f;
            sv[nf] = s;
            mrow = fmaxf(mrow, s);
        }
        #pragma unroll
        for (int off = 1; off <= 8; off <<= 1) mrow = fmaxf(mrow, __shfl_xor(mrow, off));
        float ls = 0.f;
        #pragma unroll
        for (int nf = 0; nf < 6; ++nf) {
            float pp = __expf(sv[nf] - mrow);
            pp = (sv[nf] > -1.0e29f) ? pp : 0.f;
            sv[nf] = pp;
            ls += pp;
        }
        #pragma unroll
        for (int off = 1; off <= 8; off <<= 1) ls += __shfl_xor(ls, off);
        const float rinv = (ls > 0.f) ? 1.f / ls : 0.f;
        #pragma unroll
        for (int nf = 0; nf < 6; ++nf)
            *(unsigned short*)(sm + ri * 208 + (nf * 16 + lr) * 2) = f2bf(sv[nf] * rinv);
    }

    f32x4 oacc[4] = {};
    #pragma unroll
    for (int ks = 0; ks < 3; ++ks) {
        const bf16x8 pah = *(const bf16x8*)(sm + (w * 16 + lr) * 208 + ks * 64 + lg * 16);
        #pragma unroll
        for (int nf2 = 0; nf2 < 4; ++nf2) {
            const int dd = nf2 * 16 + lr;
            const int fold = ((dd >> 3) ^ dd) & 7;
            const bf16x8 vb = *(const bf16x8*)(sm + VT_OFF + dd * 256 + (((4 * ks + lg) ^ fold) << 4));
            oacc[nf2] = __builtin_amdgcn_mfma_f32_16x16x32_bf16(pah, vb, oacc[nf2], 0, 0, 0);
        }
    }

    #pragma unroll
    for (int nf2 = 0; nf2 < 4; ++nf2) {
        #pragma unroll
        for (int r = 0; r < 4; ++r) {
            const int ri = w * 16 + lg * 4 + r;
            aoh[((size_t)(n * W_SEQ + i0 + ri)) * ATTND + h * 64 + nf2 * 16 + lr] = f2bf(oacc[nf2][r]);
        }
    }
}

// ---------------------------------------------------------------------------
// Fused persistent kernel: tree barrier after P0, then fine-grained
// producer-consumer flags (P1->P2 via qdone, P2->P3 via adone).
// REQUIRES gridDim.x == 1024 fully co-resident (host-verified occ >= 4).
// Deadlock-free: P1 never waits; P2 waits only on qdone (set by P1);
// P3 waits only on adone (set by P2). All blocks resident.
// ---------------------------------------------------------------------------
__global__ __launch_bounds__(256, 4) void fused_all_k(
    const float* __restrict__ input, const float* __restrict__ mask,
    const float* __restrict__ W_in,  const float* __restrict__ b_in,
    const float* __restrict__ W_fc,  const float* __restrict__ b_fc,
    float* __restrict__ out,
    unsigned short* __restrict__ QKVh, unsigned short* __restrict__ AOh,
    unsigned short* __restrict__ Winh, unsigned short* __restrict__ Wfch,
    unsigned short* __restrict__ Xh, unsigned* __restrict__ flg)
{
    __shared__ __align__(16) char sm[32768];
    const int b = blockIdx.x;
    unsigned* qdone = flg + 2048;   // byte 8192
    unsigned* adone = flg + 3072;   // byte 12288

    // ---- P0: prep (all 1024 blocks, one unit each) ----
    prep_unit(sm, b, input, Xh, W_in, Winh, W_fc, Wfch);
    tree_barrier(flg);

    // ---- P1: GEMM1 (768 tiles, XCD-grouped remap) ----
    if (b < 768) {
        const int y8 = b & 7, r = b >> 3;
        const int by = (r / 12) * 8 + y8;
        gemm_body<0>(sm, r % 12, by, Xh, Winh, b_in, QKVh, QKV_CH);
        __syncthreads();
        if (threadIdx.x == 0) {
            __threadfence();
            atomicAdd(qdone + by * 16, 1u);
        }
    }

    // ---- P2: attention (all 1024 blocks, one tile each) ----
    {
        const int n = b >> 8, i0 = (b & 31) * 64;
        const int row1 = n * W_SEQ + ((i0 >= 16) ? i0 - 16 : 0);
        const int row2 = n * W_SEQ + ((i0 + 79 <= W_SEQ - 1) ? i0 + 79 : W_SEQ - 1);
        const int t1 = row1 >> 7, t2 = row2 >> 7;
        if (threadIdx.x == 0) {
            while (ld_flag(qdone + t1 * 16) < 12u) __builtin_amdgcn_s_sleep(2);
            while (ld_flag(qdone + t2 * 16) < 12u) __builtin_amdgcn_s_sleep(2);
            __threadfence();
        }
        __syncthreads();
        attn_body(sm, b, QKVh, mask, AOh);
        __syncthreads();
        if (threadIdx.x == 0) {
            __threadfence();
            const int panel = n * 16 + (i0 >> 7);
            atomicAdd(adone + panel * 16, 1u);
        }
    }

    // ---- P3: GEMM2 (256 tiles) ----
    if (b < 256) {
        const int bx = b >> 2, by = b & 3;
        if (threadIdx.x == 0) {
            while (ld_flag(adone + bx * 16) < 16u) __builtin_amdgcn_s_sleep(2);
            __threadfence();
        }
        __syncthreads();
        gemm_body<1>(sm, bx, by, Wfch, AOh, b_fc, out, 0);
    }
}

// ---------------------------------------------------------------------------
// Fallback separate kernels (proven path) over the same bodies.
// ---------------------------------------------------------------------------
__global__ __launch_bounds__(256, 4) void prep_sep_k(
    const float* __restrict__ input, unsigned short* __restrict__ Xh,
    const float* __restrict__ W_in, unsigned short* __restrict__ Winh,
    const float* __restrict__ W_fc, unsigned short* __restrict__ Wfch)
{
    __shared__ __align__(16) char sm[32768];
    prep_unit(sm, blockIdx.x, input, Xh, W_in, Winh, W_fc, Wfch);
}
__global__ __launch_bounds__(256, 4) void gemm1_sep_k(
    const unsigned short* __restrict__ A, const unsigned short* __restrict__ B,
    const float* __restrict__ bias, unsigned short* __restrict__ C)
{
    __shared__ __align__(16) char sm[32768];
    const int d = blockIdx.x, y8 = d & 7, r = d >> 3;
    gemm_body<0>(sm, r % 12, (r / 12) * 8 + y8, A, B, bias, C, QKV_CH);
}
__global__ __launch_bounds__(256, 4) void attn_sep_k(
    const unsigned short* __restrict__ qkv, const float* __restrict__ mask,
    unsigned short* __restrict__ aoh)
{
    __shared__ __align__(16) char sm[32768];
    attn_body(sm, blockIdx.x, qkv, mask, aoh);
}
__global__ __launch_bounds__(256, 4) void gemm2_sep_k(
    const unsigned short* __restrict__ A, const unsigned short* __restrict__ B,
    const float* __restrict__ bias, float* __restrict__ out)
{
    __shared__ __align__(16) char sm[32768];
    gemm_body<1>(sm, blockIdx.x >> 2, blockIdx.x & 3, A, B, bias, out, 0);
}

extern "C" void kernel_launch(void* const* d_in, const int* in_sizes, int n_in,
                              void* d_out, int out_size, void* d_ws, size_t ws_size,
                              hipStream_t stream)
{
    const float* input = (const float*)d_in[0];
    const float* mask  = (const float*)d_in[1];
    const float* W_in  = (const float*)d_in[2];
    const float* b_in  = (const float*)d_in[3];
    const float* W_fc  = (const float*)d_in[4];
    const float* b_fc  = (const float*)d_in[5];
    float* out = (float*)d_out;
    char* ws = (char*)d_ws;

    // Workspace layout:
    //   QKVh [0,        25165824)  bf16[8192][1536]
    //   AOh  [25165824, 33554432)  bf16[8192][512]
    //   Winh [33554432, 35127296)  bf16[1536][512]
    //   Wfch [35127296, 35651584)  bf16[512][512]
    //   Xh   [35651584, 44040192)  bf16[8192][512]
    //   flg  [46137344, 46153728)  16 KB flag region (leaf/root/qdone/adone)
    unsigned short* QKVh = (unsigned short*)ws;
    unsigned short* AOh  = (unsigned short*)(ws + 25165824);
    unsigned short* Winh = (unsigned short*)(ws + 33554432);
    unsigned short* Wfch = (unsigned short*)(ws + 35127296);
    unsigned short* Xh   = (unsigned short*)(ws + 35651584);
    unsigned*       flg  = (unsigned*)(ws + 46137344);

    // Host-side occupancy check (pure query, deterministic, capture-safe).
    int occ = 0;
    hipOccupancyMaxActiveBlocksPerMultiprocessor(&occ, fused_all_k, 256, 0);

    if (occ >= 4) {
        hipMemsetAsync(flg, 0, 16384, stream);
        fused_all_k<<<dim3(1024), 256, 0, stream>>>(
            input, mask, W_in, b_in, W_fc, b_fc, out,
            QKVh, AOh, Winh, Wfch, Xh, flg);
    } else {
        prep_sep_k <<<dim3(1024), 256, 0, stream>>>(input, Xh, W_in, Winh, W_fc, Wfch);
        gemm1_sep_k<<<dim3(768),  256, 0, stream>>>(Xh, Winh, b_in, QKVh);
        attn_sep_k <<<dim3(1024), 256, 0, stream>>>(QKVh, mask, AOh);
        gemm2_sep_k<<<dim3(256),  256, 0, stream>>>(Wfch, AOh, b_fc, out);
    }
}